// Round 19
// baseline (327.980 us; speedup 1.0000x reference)
//
#include <hip/hip_runtime.h>
#include <hip/hip_bf16.h>
#include <hip/hip_fp16.h>

#define N_NODES 50000
#define N_EDGES 800000
#define IN_DIM 128
#define F_SIZE 64
#define N_GRAPHS 512
#define OUT_DIM 10
#define EDGE_CHUNK 2048
#define NCHUNKS ((N_EDGES + EDGE_CHUNK - 1) / EDGE_CHUNK)   // 391
#define NODES_PER_XCD ((N_NODES + 7) / 8)                    // 6250
#define GEMM_BLOCKS 782        // ceil(50000/64)
#define SCATTER_GRID (NCHUNKS * 8)                           // 3128
#define CAP 48                 // per-node CSR bucket capacity (max degree ~45 @ Poisson(16))

// ---------------- bf16 pack/unpack helpers (round-to-nearest-even) ----------------
__device__ __forceinline__ unsigned int pack_bf2(float a, float b) {
    unsigned int ua = __float_as_uint(a);
    unsigned int ub = __float_as_uint(b);
    ua += 0x7fffu + ((ua >> 16) & 1u);
    ub += 0x7fffu + ((ub >> 16) & 1u);
    return (ua >> 16) | (ub & 0xffff0000u);
}
__device__ __forceinline__ uint2 pack_f4(float4 o) {
    return make_uint2(pack_bf2(o.x, o.y), pack_bf2(o.z, o.w));
}
__device__ __forceinline__ float4 unpack_f4(uint2 u) {
    float4 f;
    f.x = __uint_as_float(u.x << 16);
    f.y = __uint_as_float(u.x & 0xffff0000u);
    f.z = __uint_as_float(u.y << 16);
    f.w = __uint_as_float(u.y & 0xffff0000u);
    return f;
}

// ---------------- utility ----------------
__global__ void k_zero_int(int* __restrict__ p, int n) {
    int i = blockIdx.x * blockDim.x + threadIdx.x;
    if (i < n) p[i] = 0;
}

// ---------------- fused: XCD-partitioned scatter + layer-1 triple GEMM (BK=32) ----------------
// R12's fusion failed at 33.8KB LDS (4 blocks/CU -> scatter starved). BK=32 gives
// 16.9KB -> ~7 blocks/CU, so latency-bound scatter blocks keep their TLP while
// GEMM blocks soak the idle VALU issue slots (R9 lesson).
#define AT_STRIDE 68
__global__ __launch_bounds__(256) void k_scatter_gemm(const int* __restrict__ ind0,
                                                      const int* __restrict__ ind1,
                                                      const float* __restrict__ vals,
                                                      int* __restrict__ cnt0, int* __restrict__ cnt1,
                                                      unsigned int* __restrict__ c0pack,
                                                      int* __restrict__ c1src,
                                                      const float* __restrict__ X,
                                                      const float* __restrict__ W1,
                                                      uint2* __restrict__ G0bf,
                                                      uint2* __restrict__ G1bf,
                                                      uint2* __restrict__ G2bf) {
    __shared__ float At[32 * AT_STRIDE];
    __shared__ float Wl[32 * 64];
    if (blockIdx.x < SCATTER_GRID) {
        // ---- scatter path ----
        int xcd = blockIdx.x & 7;
        int chunk = blockIdx.x >> 3;
        int lo = xcd * NODES_PER_XCD, hi = lo + NODES_PER_XCD;
        int base = chunk * EDGE_CHUNK;
        int end = base + EDGE_CHUNK; if (end > N_EDGES) end = N_EDGES;
        for (int e = base + threadIdx.x; e < end; e += 256) {
            int r = __builtin_nontemporal_load(&ind0[e]);
            int c = __builtin_nontemporal_load(&ind1[e]);
            if (r >= lo && r < hi) {
                int p0 = atomicAdd(&cnt0[r], 1);
                float v = __builtin_nontemporal_load(&vals[e]);
                unsigned int hv = (unsigned int)__half_as_ushort(__float2half(v));
                c0pack[r * CAP + p0] = ((unsigned int)c << 16) | hv;
            }
            if (c >= lo && c < hi) {
                int p1 = atomicAdd(&cnt1[c], 1);
                c1src[c * CAP + p1] = r;
            }
        }
        return;
    }
    // ---- GEMM path ----
    const int t = threadIdx.x;
    const int l = t & 63, w = t >> 6;
    const int r0 = (blockIdx.x - SCATTER_GRID) * 64;
    const int rbase = w * 16 + (l >> 4) * 4;
    const int cbase = (l & 15) * 4;
    float acc[3][4][4] = {};

    #pragma unroll
    for (int ch = 0; ch < 4; ++ch) {
        const int koff = ch * 32;
        #pragma unroll
        for (int i = 0; i < 2; ++i) {
            int f   = i * 256 + t;
            int row = f >> 3;
            int kq  = f & 7;
            int gr  = r0 + row; if (gr > N_NODES - 1) gr = N_NODES - 1;
            float4 v = *(const float4*)(X + (size_t)gr * IN_DIM + koff + kq * 4);
            At[(kq * 4 + 0) * AT_STRIDE + row] = v.x;
            At[(kq * 4 + 1) * AT_STRIDE + row] = v.y;
            At[(kq * 4 + 2) * AT_STRIDE + row] = v.z;
            At[(kq * 4 + 3) * AT_STRIDE + row] = v.w;
        }
        #pragma unroll
        for (int sg = 0; sg < 3; ++sg) {
            const float4* Wg = (const float4*)(W1 + ((size_t)sg * 128 + koff) * 64);
            float4 wtmp[2];
            #pragma unroll
            for (int i = 0; i < 2; ++i) wtmp[i] = Wg[i * 256 + t];
            __syncthreads();
            #pragma unroll
            for (int i = 0; i < 2; ++i) *(float4*)&Wl[(i * 256 + t) * 4] = wtmp[i];
            __syncthreads();
            #pragma unroll 8
            for (int k = 0; k < 32; ++k) {
                float4 a4 = *(const float4*)&At[k * AT_STRIDE + rbase];
                float4 w4 = *(const float4*)&Wl[k * 64 + cbase];
                acc[sg][0][0] += a4.x * w4.x; acc[sg][0][1] += a4.x * w4.y; acc[sg][0][2] += a4.x * w4.z; acc[sg][0][3] += a4.x * w4.w;
                acc[sg][1][0] += a4.y * w4.x; acc[sg][1][1] += a4.y * w4.y; acc[sg][1][2] += a4.y * w4.z; acc[sg][1][3] += a4.y * w4.w;
                acc[sg][2][0] += a4.z * w4.x; acc[sg][2][1] += a4.z * w4.y; acc[sg][2][2] += a4.z * w4.z; acc[sg][2][3] += a4.z * w4.w;
                acc[sg][3][0] += a4.w * w4.x; acc[sg][3][1] += a4.w * w4.y; acc[sg][3][2] += a4.w * w4.z; acc[sg][3][3] += a4.w * w4.w;
            }
        }
        __syncthreads();
    }
    uint2* Gs[3] = {G0bf, G1bf, G2bf};
    #pragma unroll
    for (int sg = 0; sg < 3; ++sg) {
        #pragma unroll
        for (int r = 0; r < 4; ++r) {
            int gr = r0 + rbase + r;
            if (gr < N_NODES) {
                float4 o = {acc[sg][r][0], acc[sg][r][1], acc[sg][r][2], acc[sg][r][3]};
                Gs[sg][(size_t)gr * 16 + (l & 15)] = pack_f4(o);
            }
        }
    }
}

// ---------------- bf16-gather SpMM: wave = 4 nodes, 16 lanes/row ----------------
// MODE 0: Rbf = A(G1bf) + 2*acc(src=G2bf)
// MODE 1: hbf = dis*(acc(src=Rbf) + A(G0bf) - B(G2bf))
template<int MODE>
__global__ __launch_bounds__(256) void k_spmm64v(const int* __restrict__ cnt0,
                          const unsigned int* __restrict__ pack,
                          const uint2* __restrict__ srcbf, const uint2* __restrict__ Abf,
                          const uint2* __restrict__ Bbf, const int* __restrict__ cnt1,
                          uint2* __restrict__ dstbf) {
    int t = blockIdx.x * blockDim.x + threadIdx.x;
    int wid = t >> 6, lane = t & 63;
    int grp = lane >> 4, sub = lane & 15;
    int node = wid * 4 + grp;
    if (node >= N_NODES) return;
    int s = node * CAP;
    int e = s + cnt0[node];
    float4 acc = {0.f, 0.f, 0.f, 0.f};
    int j = s;
    for (; j + 3 < e; j += 4) {
        unsigned int p0 = pack[j], p1 = pack[j + 1], p2 = pack[j + 2], p3 = pack[j + 3];
        float4 r0 = unpack_f4(srcbf[(size_t)(p0 >> 16) * 16 + sub]);
        float4 r1 = unpack_f4(srcbf[(size_t)(p1 >> 16) * 16 + sub]);
        float4 r2 = unpack_f4(srcbf[(size_t)(p2 >> 16) * 16 + sub]);
        float4 r3 = unpack_f4(srcbf[(size_t)(p3 >> 16) * 16 + sub]);
        float v0 = __half2float(__ushort_as_half((unsigned short)(p0 & 0xffffu)));
        float v1 = __half2float(__ushort_as_half((unsigned short)(p1 & 0xffffu)));
        float v2 = __half2float(__ushort_as_half((unsigned short)(p2 & 0xffffu)));
        float v3 = __half2float(__ushort_as_half((unsigned short)(p3 & 0xffffu)));
        acc.x += v0 * r0.x + v1 * r1.x + v2 * r2.x + v3 * r3.x;
        acc.y += v0 * r0.y + v1 * r1.y + v2 * r2.y + v3 * r3.y;
        acc.z += v0 * r0.z + v1 * r1.z + v2 * r2.z + v3 * r3.z;
        acc.w += v0 * r0.w + v1 * r1.w + v2 * r2.w + v3 * r3.w;
    }
    for (; j < e; ++j) {
        unsigned int p = pack[j];
        float4 r = unpack_f4(srcbf[(size_t)(p >> 16) * 16 + sub]);
        float v = __half2float(__ushort_as_half((unsigned short)(p & 0xffffu)));
        acc.x += v * r.x; acc.y += v * r.y; acc.z += v * r.z; acc.w += v * r.w;
    }
    size_t idx = (size_t)node * 16 + sub;
    float4 a = unpack_f4(Abf[idx]);
    float4 o;
    if (MODE == 0) {
        o.x = a.x + 2.f * acc.x; o.y = a.y + 2.f * acc.y;
        o.z = a.z + 2.f * acc.z; o.w = a.w + 2.f * acc.w;
    } else {
        float4 bb = unpack_f4(Bbf[idx]);
        float d = rsqrtf(1.0f + (float)cnt1[node]);
        o.x = d * (acc.x + a.x - bb.x); o.y = d * (acc.y + a.y - bb.y);
        o.z = d * (acc.z + a.z - bb.z); o.w = d * (acc.w + a.w - bb.w);
    }
    dstbf[idx] = pack_f4(o);
}

// ---------------- bf16-gather conv ----------------
// FINAL=0: xbf = bf16(relu(dis*(acc + self) + b))
// FINAL=1: xm  = (x1 + x2 + relu(...))/3   (fp32, feeds pool only)
template<int FINAL>
__global__ void k_conv_gatherv(const int* __restrict__ cnt1, const int* __restrict__ csrc,
                               const uint2* __restrict__ hbf,
                               const float* __restrict__ b,
                               const uint2* __restrict__ x1bf, const uint2* __restrict__ x2bf,
                               uint2* __restrict__ outbf, float4* __restrict__ outf) {
    int t = blockIdx.x * blockDim.x + threadIdx.x;
    int wid = t >> 6, lane = t & 63;
    int grp = lane >> 4, sub = lane & 15;
    int node = wid * 4 + grp;
    if (node >= N_NODES) return;
    int deg = cnt1[node];
    int s = node * CAP;
    int e = s + deg;
    float4 acc = {0.f, 0.f, 0.f, 0.f};
    int j = s;
    for (; j + 3 < e; j += 4) {
        int s0 = csrc[j], s1 = csrc[j + 1], s2 = csrc[j + 2], s3 = csrc[j + 3];
        float4 r0 = unpack_f4(hbf[(size_t)s0 * 16 + sub]);
        float4 r1 = unpack_f4(hbf[(size_t)s1 * 16 + sub]);
        float4 r2 = unpack_f4(hbf[(size_t)s2 * 16 + sub]);
        float4 r3 = unpack_f4(hbf[(size_t)s3 * 16 + sub]);
        acc.x += (r0.x + r1.x) + (r2.x + r3.x);
        acc.y += (r0.y + r1.y) + (r2.y + r3.y);
        acc.z += (r0.z + r1.z) + (r2.z + r3.z);
        acc.w += (r0.w + r1.w) + (r2.w + r3.w);
    }
    for (; j < e; ++j) {
        float4 r = unpack_f4(hbf[(size_t)csrc[j] * 16 + sub]);
        acc.x += r.x; acc.y += r.y; acc.z += r.z; acc.w += r.w;
    }
    size_t idx = (size_t)node * 16 + sub;
    float4 sl = unpack_f4(hbf[idx]);      // self loop
    float d = rsqrtf(1.0f + (float)deg);
    float4 bv = ((const float4*)b)[sub];
    float4 o;
    o.x = fmaxf(d * (acc.x + sl.x) + bv.x, 0.f);
    o.y = fmaxf(d * (acc.y + sl.y) + bv.y, 0.f);
    o.z = fmaxf(d * (acc.z + sl.z) + bv.z, 0.f);
    o.w = fmaxf(d * (acc.w + sl.w) + bv.w, 0.f);
    if (FINAL) {
        float4 a1 = unpack_f4(x1bf[idx]), a2 = unpack_f4(x2bf[idx]);
        const float third = 1.f / 3.f;
        o.x = (a1.x + a2.x + o.x) * third;
        o.y = (a1.y + a2.y + o.y) * third;
        o.z = (a1.z + a2.z + o.z) * third;
        o.w = (a1.w + a2.w + o.w) * third;
        outf[idx] = o;
    } else {
        outbf[idx] = pack_f4(o);
    }
}

// ---------------- LDS-tiled GEMM BK=32: hbf = dis ⊙ (s0bf @ W), bf16 in/out ----------------
__global__ __launch_bounds__(256) void k_gemm64(const uint2* __restrict__ s0bf,
                                                const float* __restrict__ W,
                                                const int* __restrict__ cnt1,
                                                uint2* __restrict__ Cbf) {
    __shared__ float At[32 * AT_STRIDE];
    __shared__ float Wl[32 * 64];
    const int t = threadIdx.x;
    const int l = t & 63, w = t >> 6;
    const int r0 = blockIdx.x * 64;
    const int rbase = w * 16 + (l >> 4) * 4;
    const int cbase = (l & 15) * 4;
    float acc[4][4] = {};

    #pragma unroll
    for (int ch = 0; ch < 2; ++ch) {
        const int koff = ch * 32;      // floats; = ch*8 uint2
        #pragma unroll
        for (int i = 0; i < 2; ++i) {
            int f   = i * 256 + t;
            int row = f >> 3;
            int kq  = f & 7;
            int gr  = r0 + row; if (gr > N_NODES - 1) gr = N_NODES - 1;
            float4 v = unpack_f4(s0bf[(size_t)gr * 16 + (koff >> 2) + kq]);
            At[(kq * 4 + 0) * AT_STRIDE + row] = v.x;
            At[(kq * 4 + 1) * AT_STRIDE + row] = v.y;
            At[(kq * 4 + 2) * AT_STRIDE + row] = v.z;
            At[(kq * 4 + 3) * AT_STRIDE + row] = v.w;
        }
        {
            const float4* Wg = (const float4*)(W + (size_t)koff * 64);
            float4 wtmp[2];
            #pragma unroll
            for (int i = 0; i < 2; ++i) wtmp[i] = Wg[i * 256 + t];
            __syncthreads();
            #pragma unroll
            for (int i = 0; i < 2; ++i) *(float4*)&Wl[(i * 256 + t) * 4] = wtmp[i];
            __syncthreads();
        }
        #pragma unroll 8
        for (int k = 0; k < 32; ++k) {
            float4 a4 = *(const float4*)&At[k * AT_STRIDE + rbase];
            float4 w4 = *(const float4*)&Wl[k * 64 + cbase];
            acc[0][0] += a4.x * w4.x; acc[0][1] += a4.x * w4.y; acc[0][2] += a4.x * w4.z; acc[0][3] += a4.x * w4.w;
            acc[1][0] += a4.y * w4.x; acc[1][1] += a4.y * w4.y; acc[1][2] += a4.y * w4.z; acc[1][3] += a4.y * w4.w;
            acc[2][0] += a4.z * w4.x; acc[2][1] += a4.z * w4.y; acc[2][2] += a4.z * w4.z; acc[2][3] += a4.z * w4.w;
            acc[3][0] += a4.w * w4.x; acc[3][1] += a4.w * w4.y; acc[3][2] += a4.w * w4.z; acc[3][3] += a4.w * w4.w;
        }
        __syncthreads();
    }
    #pragma unroll
    for (int r = 0; r < 4; ++r) {
        int gr = r0 + rbase + r;
        if (gr < N_NODES) {
            float d = rsqrtf(1.0f + (float)cnt1[gr]);
            float4 o = {d * acc[r][0], d * acc[r][1], d * acc[r][2], d * acc[r][3]};
            Cbf[(size_t)gr * 16 + (l & 15)] = pack_f4(o);
        }
    }
}

// ---------------- pool (batch sorted -> contiguous ranges) + head, 4 waves ----------------
__global__ __launch_bounds__(256) void k_pool_out(const float* __restrict__ xm,
                           const int* __restrict__ batch,
                           const float* __restrict__ Wout, const float* __restrict__ bout,
                           float* __restrict__ out) {
    __shared__ float red[4][64];
    __shared__ float sh[64];
    __shared__ float logits[OUT_DIM];
    int g = blockIdx.x;
    int t = threadIdx.x, f = t & 63, w = t >> 6;
    int lo = 0, hi = N_NODES;
    while (lo < hi) { int m = (lo + hi) >> 1; if (batch[m] < g) lo = m + 1; else hi = m; }
    int start = lo;
    hi = N_NODES;
    while (lo < hi) { int m = (lo + hi) >> 1; if (batch[m] < g + 1) lo = m + 1; else hi = m; }
    int end = lo;
    float a = 0.f;
    for (int i = start + w; i < end; i += 4)
        a += xm[(size_t)i * 64 + f];
    red[w][f] = a;
    __syncthreads();
    if (w == 0) {
        float cnt = (float)((end - start) > 0 ? (end - start) : 1);
        sh[f] = (red[0][f] + red[1][f] + red[2][f] + red[3][f]) / cnt;
    }
    __syncthreads();
    if (t < OUT_DIM) {
        float l = bout[t];
        for (int k = 0; k < 64; ++k) l += sh[k] * Wout[k * OUT_DIM + t];
        logits[t] = l;
    }
    __syncthreads();
    if (t < OUT_DIM) {
        float m = logits[0];
        for (int k = 1; k < OUT_DIM; ++k) m = fmaxf(m, logits[k]);
        float ssum = 0.f;
        for (int k = 0; k < OUT_DIM; ++k) ssum += expf(logits[k] - m);
        out[(size_t)g * OUT_DIM + t] = expf(logits[t] - m) / ssum;
    }
}

extern "C" void kernel_launch(void* const* d_in, const int* in_sizes, int n_in,
                              void* d_out, int out_size, void* d_ws, size_t ws_size,
                              hipStream_t stream) {
    const float* X     = (const float*)d_in[0];
    const int*   Lind  = (const int*)d_in[1];
    const int*   ind0  = Lind;
    const int*   ind1  = Lind + N_EDGES;
    const float* vals  = (const float*)d_in[2];
    const int*   batch = (const int*)d_in[3];
    const float* W1    = (const float*)d_in[4];
    const float* b1    = (const float*)d_in[5];
    const float* W2    = (const float*)d_in[6];
    const float* b2    = (const float*)d_in[7];
    const float* W3    = (const float*)d_in[8];
    const float* b3    = (const float*)d_in[9];
    const float* Wout  = (const float*)d_in[10];
    const float* bout  = (const float*)d_in[11];
    float* out = (float*)d_out;

    // workspace layout (4B words)
    int* cnt0    = (int*)d_ws;                     // 50000
    int* cnt1    = cnt0 + 50000;                   // 50000
    unsigned int* c0pack = (unsigned int*)(cnt1 + 50000);  // 2,400,000 u32
    int*  c1src  = (int*)(c0pack + 50000 * CAP);   // 2,400,000
    uint2* G0bf  = (uint2*)(c1src + 50000 * CAP);  // 800,000 uint2
    uint2* G1bf  = G0bf + 800000;
    uint2* G2bf  = G1bf + 800000;
    uint2* Rbf   = G2bf + 800000;
    uint2* hbf   = Rbf + 800000;
    float* xm    = (float*)(hbf + 800000);         // 3,200,000 fp32
    // bf16 buffer reuse after producers die:
    uint2* x1bf  = G0bf;   // G0 dead after spmm1
    uint2* x2bf  = G1bf;   // G1 dead after spmm0

    const int B = 256;
    const int gatherGrid = 12500 * 64 / B;                // 3125 blocks (4 nodes/wave)
    const int tileGrid = GEMM_BLOCKS;                     // 782

    // zero counters, then fused {CSR scatter + layer-1 GEMM} (co-scheduled)
    k_zero_int<<<(100000 + B - 1) / B, B, 0, stream>>>(cnt0, 100000);  // cnt0+cnt1 contiguous
    k_scatter_gemm<<<SCATTER_GRID + tileGrid, B, 0, stream>>>(ind0, ind1, vals, cnt0, cnt1,
                                                              c0pack, c1src,
                                                              X, W1, G0bf, G1bf, G2bf);

    // Chebyshev via linearity (64-dim spmms, bf16 gathers):
    // R = G1 + 2*(L@G2);  h1' = dis*(L@R + G0 - G2)
    k_spmm64v<0><<<gatherGrid, B, 0, stream>>>(cnt0, c0pack, G2bf, G1bf, nullptr, cnt1, Rbf);
    k_spmm64v<1><<<gatherGrid, B, 0, stream>>>(cnt0, c0pack, Rbf, G0bf, G2bf, cnt1, hbf);

    // layer 1 conv (writes x1bf into G0bf's space)
    k_conv_gatherv<0><<<gatherGrid, B, 0, stream>>>(cnt1, c1src, hbf, b1,
                                                    nullptr, nullptr, x1bf, nullptr);

    // layer 2: hbf = dis*(x1@W2), conv (x2bf into G1bf's space)
    k_gemm64<<<tileGrid, B, 0, stream>>>(x1bf, W2, cnt1, hbf);
    k_conv_gatherv<0><<<gatherGrid, B, 0, stream>>>(cnt1, c1src, hbf, b2,
                                                    nullptr, nullptr, x2bf, nullptr);

    // layer 3: conv writes xm = (x1+x2+x3)/3 (fp32)
    k_gemm64<<<tileGrid, B, 0, stream>>>(x2bf, W3, cnt1, hbf);
    k_conv_gatherv<1><<<gatherGrid, B, 0, stream>>>(cnt1, c1src, hbf, b3,
                                                    x1bf, x2bf, nullptr, (float4*)xm);

    // pool + head
    k_pool_out<<<N_GRAPHS, B, 0, stream>>>(xm, batch, Wout, bout, out);
}

// Round 20
// 295.068 us; speedup vs baseline: 1.1115x; 1.1115x over previous
//
#include <hip/hip_runtime.h>
#include <hip/hip_bf16.h>
#include <hip/hip_fp16.h>

#define N_NODES 50000
#define N_EDGES 800000
#define IN_DIM 128
#define F_SIZE 64
#define N_GRAPHS 512
#define OUT_DIM 10
#define EDGE_CHUNK 2048
#define NCHUNKS ((N_EDGES + EDGE_CHUNK - 1) / EDGE_CHUNK)   // 391
#define NODES_PER_XCD ((N_NODES + 7) / 8)                    // 6250
#define GEMM_BLOCKS 782        // ceil(50000/64)
#define CAP 48                 // per-node CSR bucket capacity (max degree ~45 @ Poisson(16))

// ---------------- bf16 pack/unpack helpers (round-to-nearest-even) ----------------
__device__ __forceinline__ unsigned int pack_bf2(float a, float b) {
    unsigned int ua = __float_as_uint(a);
    unsigned int ub = __float_as_uint(b);
    ua += 0x7fffu + ((ua >> 16) & 1u);
    ub += 0x7fffu + ((ub >> 16) & 1u);
    return (ua >> 16) | (ub & 0xffff0000u);
}
__device__ __forceinline__ uint2 pack_f4(float4 o) {
    return make_uint2(pack_bf2(o.x, o.y), pack_bf2(o.z, o.w));
}
__device__ __forceinline__ float4 unpack_f4(uint2 u) {
    float4 f;
    f.x = __uint_as_float(u.x << 16);
    f.y = __uint_as_float(u.x & 0xffff0000u);
    f.z = __uint_as_float(u.y << 16);
    f.w = __uint_as_float(u.y & 0xffff0000u);
    return f;
}

// ---------------- utility ----------------
__global__ void k_zero_int(int* __restrict__ p, int n) {
    int i = blockIdx.x * blockDim.x + threadIdx.x;
    if (i < n) p[i] = 0;
}

// ---------------- XCD-partitioned direct scatter ----------------
// c0 payload: one u32 = (col << 16) | fp16(val).  c1 payload: src node id (u32).
__global__ __launch_bounds__(256) void k_scatter_direct(const int* __restrict__ ind0,
                                                        const int* __restrict__ ind1,
                                                        const float* __restrict__ vals,
                                                        int* __restrict__ cnt0, int* __restrict__ cnt1,
                                                        unsigned int* __restrict__ c0pack,
                                                        int* __restrict__ c1src) {
    int xcd = blockIdx.x & 7;
    int chunk = blockIdx.x >> 3;
    int lo = xcd * NODES_PER_XCD, hi = lo + NODES_PER_XCD;
    int base = chunk * EDGE_CHUNK;
    int end = base + EDGE_CHUNK; if (end > N_EDGES) end = N_EDGES;
    for (int e = base + threadIdx.x; e < end; e += 256) {
        int r = ind0[e];
        int c = ind1[e];
        if (r >= lo && r < hi) {
            int p0 = atomicAdd(&cnt0[r], 1);
            unsigned int hv = (unsigned int)__half_as_ushort(__float2half(vals[e]));
            c0pack[r * CAP + p0] = ((unsigned int)c << 16) | hv;
        }
        if (c >= lo && c < hi) {
            int p1 = atomicAdd(&cnt1[c], 1);
            c1src[c * CAP + p1] = r;
        }
    }
}

// ---------------- layer-1 triple GEMM: all outputs bf16 ----------------
#define AT_STRIDE 68
__global__ __launch_bounds__(256) void k_gemm1x3(const float* __restrict__ X,
                                                 const float* __restrict__ W1,
                                                 uint2* __restrict__ G0bf,
                                                 uint2* __restrict__ G1bf,
                                                 uint2* __restrict__ G2bf) {
    __shared__ float At[64 * AT_STRIDE];
    __shared__ float Wl[64 * 64];
    const int t = threadIdx.x;
    const int l = t & 63, w = t >> 6;
    const int r0 = blockIdx.x * 64;
    const int rbase = w * 16 + (l >> 4) * 4;
    const int cbase = (l & 15) * 4;
    float acc[3][4][4] = {};

    #pragma unroll
    for (int ch = 0; ch < 2; ++ch) {
        const int koff = ch * 64;
        #pragma unroll
        for (int i = 0; i < 4; ++i) {
            int f   = i * 256 + t;
            int row = f >> 4;
            int kq  = f & 15;
            int gr  = r0 + row; if (gr > N_NODES - 1) gr = N_NODES - 1;
            float4 v = *(const float4*)(X + (size_t)gr * IN_DIM + koff + kq * 4);
            At[(kq * 4 + 0) * AT_STRIDE + row] = v.x;
            At[(kq * 4 + 1) * AT_STRIDE + row] = v.y;
            At[(kq * 4 + 2) * AT_STRIDE + row] = v.z;
            At[(kq * 4 + 3) * AT_STRIDE + row] = v.w;
        }
        #pragma unroll
        for (int sg = 0; sg < 3; ++sg) {
            const float4* Wg = (const float4*)(W1 + ((size_t)sg * 128 + koff) * 64);
            float4 wtmp[4];
            #pragma unroll
            for (int i = 0; i < 4; ++i) wtmp[i] = Wg[i * 256 + t];
            __syncthreads();
            #pragma unroll
            for (int i = 0; i < 4; ++i) *(float4*)&Wl[(i * 256 + t) * 4] = wtmp[i];
            __syncthreads();
            #pragma unroll 8
            for (int k = 0; k < 64; ++k) {
                float4 a4 = *(const float4*)&At[k * AT_STRIDE + rbase];
                float4 w4 = *(const float4*)&Wl[k * 64 + cbase];
                acc[sg][0][0] += a4.x * w4.x; acc[sg][0][1] += a4.x * w4.y; acc[sg][0][2] += a4.x * w4.z; acc[sg][0][3] += a4.x * w4.w;
                acc[sg][1][0] += a4.y * w4.x; acc[sg][1][1] += a4.y * w4.y; acc[sg][1][2] += a4.y * w4.z; acc[sg][1][3] += a4.y * w4.w;
                acc[sg][2][0] += a4.z * w4.x; acc[sg][2][1] += a4.z * w4.y; acc[sg][2][2] += a4.z * w4.z; acc[sg][2][3] += a4.z * w4.w;
                acc[sg][3][0] += a4.w * w4.x; acc[sg][3][1] += a4.w * w4.y; acc[sg][3][2] += a4.w * w4.z; acc[sg][3][3] += a4.w * w4.w;
            }
        }
        __syncthreads();
    }
    uint2* Gs[3] = {G0bf, G1bf, G2bf};
    #pragma unroll
    for (int sg = 0; sg < 3; ++sg) {
        #pragma unroll
        for (int r = 0; r < 4; ++r) {
            int gr = r0 + rbase + r;
            if (gr < N_NODES) {
                float4 o = {acc[sg][r][0], acc[sg][r][1], acc[sg][r][2], acc[sg][r][3]};
                Gs[sg][(size_t)gr * 16 + (l & 15)] = pack_f4(o);
            }
        }
    }
}

// ---------------- bf16-gather SpMM: wave = 4 nodes, 16 lanes/row ----------------
// MODE 0: Rbf = A(G1bf) + 2*acc(src=G2bf)
// MODE 1: hbf = dis*(acc(src=Rbf) + A(G0bf) - B(G2bf))
template<int MODE>
__global__ __launch_bounds__(256) void k_spmm64v(const int* __restrict__ cnt0,
                          const unsigned int* __restrict__ pack,
                          const uint2* __restrict__ srcbf, const uint2* __restrict__ Abf,
                          const uint2* __restrict__ Bbf, const int* __restrict__ cnt1,
                          uint2* __restrict__ dstbf) {
    int t = blockIdx.x * blockDim.x + threadIdx.x;
    int wid = t >> 6, lane = t & 63;
    int grp = lane >> 4, sub = lane & 15;
    int node = wid * 4 + grp;
    if (node >= N_NODES) return;
    int s = node * CAP;
    int e = s + cnt0[node];
    float4 acc = {0.f, 0.f, 0.f, 0.f};
    int j = s;
    for (; j + 3 < e; j += 4) {
        unsigned int p0 = pack[j], p1 = pack[j + 1], p2 = pack[j + 2], p3 = pack[j + 3];
        float4 r0 = unpack_f4(srcbf[(size_t)(p0 >> 16) * 16 + sub]);
        float4 r1 = unpack_f4(srcbf[(size_t)(p1 >> 16) * 16 + sub]);
        float4 r2 = unpack_f4(srcbf[(size_t)(p2 >> 16) * 16 + sub]);
        float4 r3 = unpack_f4(srcbf[(size_t)(p3 >> 16) * 16 + sub]);
        float v0 = __half2float(__ushort_as_half((unsigned short)(p0 & 0xffffu)));
        float v1 = __half2float(__ushort_as_half((unsigned short)(p1 & 0xffffu)));
        float v2 = __half2float(__ushort_as_half((unsigned short)(p2 & 0xffffu)));
        float v3 = __half2float(__ushort_as_half((unsigned short)(p3 & 0xffffu)));
        acc.x += v0 * r0.x + v1 * r1.x + v2 * r2.x + v3 * r3.x;
        acc.y += v0 * r0.y + v1 * r1.y + v2 * r2.y + v3 * r3.y;
        acc.z += v0 * r0.z + v1 * r1.z + v2 * r2.z + v3 * r3.z;
        acc.w += v0 * r0.w + v1 * r1.w + v2 * r2.w + v3 * r3.w;
    }
    for (; j < e; ++j) {
        unsigned int p = pack[j];
        float4 r = unpack_f4(srcbf[(size_t)(p >> 16) * 16 + sub]);
        float v = __half2float(__ushort_as_half((unsigned short)(p & 0xffffu)));
        acc.x += v * r.x; acc.y += v * r.y; acc.z += v * r.z; acc.w += v * r.w;
    }
    size_t idx = (size_t)node * 16 + sub;
    float4 a = unpack_f4(Abf[idx]);
    float4 o;
    if (MODE == 0) {
        o.x = a.x + 2.f * acc.x; o.y = a.y + 2.f * acc.y;
        o.z = a.z + 2.f * acc.z; o.w = a.w + 2.f * acc.w;
    } else {
        float4 bb = unpack_f4(Bbf[idx]);
        float d = rsqrtf(1.0f + (float)cnt1[node]);
        o.x = d * (acc.x + a.x - bb.x); o.y = d * (acc.y + a.y - bb.y);
        o.z = d * (acc.z + a.z - bb.z); o.w = d * (acc.w + a.w - bb.w);
    }
    dstbf[idx] = pack_f4(o);
}

// ---------------- bf16-gather conv ----------------
// FINAL=0: xbf = bf16(relu(dis*(acc + self) + b))
// FINAL=1: xm  = (x1 + x2 + relu(...))/3   (fp32, feeds pool only)
template<int FINAL>
__global__ void k_conv_gatherv(const int* __restrict__ cnt1, const int* __restrict__ csrc,
                               const uint2* __restrict__ hbf,
                               const float* __restrict__ b,
                               const uint2* __restrict__ x1bf, const uint2* __restrict__ x2bf,
                               uint2* __restrict__ outbf, float4* __restrict__ outf) {
    int t = blockIdx.x * blockDim.x + threadIdx.x;
    int wid = t >> 6, lane = t & 63;
    int grp = lane >> 4, sub = lane & 15;
    int node = wid * 4 + grp;
    if (node >= N_NODES) return;
    int deg = cnt1[node];
    int s = node * CAP;
    int e = s + deg;
    float4 acc = {0.f, 0.f, 0.f, 0.f};
    int j = s;
    for (; j + 3 < e; j += 4) {
        int s0 = csrc[j], s1 = csrc[j + 1], s2 = csrc[j + 2], s3 = csrc[j + 3];
        float4 r0 = unpack_f4(hbf[(size_t)s0 * 16 + sub]);
        float4 r1 = unpack_f4(hbf[(size_t)s1 * 16 + sub]);
        float4 r2 = unpack_f4(hbf[(size_t)s2 * 16 + sub]);
        float4 r3 = unpack_f4(hbf[(size_t)s3 * 16 + sub]);
        acc.x += (r0.x + r1.x) + (r2.x + r3.x);
        acc.y += (r0.y + r1.y) + (r2.y + r3.y);
        acc.z += (r0.z + r1.z) + (r2.z + r3.z);
        acc.w += (r0.w + r1.w) + (r2.w + r3.w);
    }
    for (; j < e; ++j) {
        float4 r = unpack_f4(hbf[(size_t)csrc[j] * 16 + sub]);
        acc.x += r.x; acc.y += r.y; acc.z += r.z; acc.w += r.w;
    }
    size_t idx = (size_t)node * 16 + sub;
    float4 sl = unpack_f4(hbf[idx]);      // self loop
    float d = rsqrtf(1.0f + (float)deg);
    float4 bv = ((const float4*)b)[sub];
    float4 o;
    o.x = fmaxf(d * (acc.x + sl.x) + bv.x, 0.f);
    o.y = fmaxf(d * (acc.y + sl.y) + bv.y, 0.f);
    o.z = fmaxf(d * (acc.z + sl.z) + bv.z, 0.f);
    o.w = fmaxf(d * (acc.w + sl.w) + bv.w, 0.f);
    if (FINAL) {
        float4 a1 = unpack_f4(x1bf[idx]), a2 = unpack_f4(x2bf[idx]);
        const float third = 1.f / 3.f;
        o.x = (a1.x + a2.x + o.x) * third;
        o.y = (a1.y + a2.y + o.y) * third;
        o.z = (a1.z + a2.z + o.z) * third;
        o.w = (a1.w + a2.w + o.w) * third;
        outf[idx] = o;
    } else {
        outbf[idx] = pack_f4(o);
    }
}

// ---------------- LDS-tiled GEMM: hbf = dis ⊙ (s0bf @ W), bf16 in/out ----------------
__global__ __launch_bounds__(256) void k_gemm64(const uint2* __restrict__ s0bf,
                                                const float* __restrict__ W,
                                                const int* __restrict__ cnt1,
                                                uint2* __restrict__ Cbf) {
    __shared__ float At[64 * AT_STRIDE];
    __shared__ float Wl[64 * 64];
    const int t = threadIdx.x;
    const int l = t & 63, w = t >> 6;
    const int r0 = blockIdx.x * 64;
    const int rbase = w * 16 + (l >> 4) * 4;
    const int cbase = (l & 15) * 4;
    float acc[4][4] = {};

    {
        const float4* Wg = (const float4*)W;
        #pragma unroll
        for (int i = 0; i < 4; ++i) *(float4*)&Wl[(i * 256 + t) * 4] = Wg[i * 256 + t];
    }
    #pragma unroll
    for (int i = 0; i < 4; ++i) {
        int f   = i * 256 + t;
        int row = f >> 4;
        int kq  = f & 15;
        int gr  = r0 + row; if (gr > N_NODES - 1) gr = N_NODES - 1;
        float4 v = unpack_f4(s0bf[(size_t)gr * 16 + kq]);
        At[(kq * 4 + 0) * AT_STRIDE + row] = v.x;
        At[(kq * 4 + 1) * AT_STRIDE + row] = v.y;
        At[(kq * 4 + 2) * AT_STRIDE + row] = v.z;
        At[(kq * 4 + 3) * AT_STRIDE + row] = v.w;
    }
    __syncthreads();
    #pragma unroll 8
    for (int k = 0; k < 64; ++k) {
        float4 a4 = *(const float4*)&At[k * AT_STRIDE + rbase];
        float4 w4 = *(const float4*)&Wl[k * 64 + cbase];
        acc[0][0] += a4.x * w4.x; acc[0][1] += a4.x * w4.y; acc[0][2] += a4.x * w4.z; acc[0][3] += a4.x * w4.w;
        acc[1][0] += a4.y * w4.x; acc[1][1] += a4.y * w4.y; acc[1][2] += a4.y * w4.z; acc[1][3] += a4.y * w4.w;
        acc[2][0] += a4.z * w4.x; acc[2][1] += a4.z * w4.y; acc[2][2] += a4.z * w4.z; acc[2][3] += a4.z * w4.w;
        acc[3][0] += a4.w * w4.x; acc[3][1] += a4.w * w4.y; acc[3][2] += a4.w * w4.z; acc[3][3] += a4.w * w4.w;
    }
    #pragma unroll
    for (int r = 0; r < 4; ++r) {
        int gr = r0 + rbase + r;
        if (gr < N_NODES) {
            float d = rsqrtf(1.0f + (float)cnt1[gr]);
            float4 o = {d * acc[r][0], d * acc[r][1], d * acc[r][2], d * acc[r][3]};
            Cbf[(size_t)gr * 16 + (l & 15)] = pack_f4(o);
        }
    }
}

// ---------------- pool (batch sorted -> contiguous ranges) + head, 4 waves ----------------
__global__ __launch_bounds__(256) void k_pool_out(const float* __restrict__ xm,
                           const int* __restrict__ batch,
                           const float* __restrict__ Wout, const float* __restrict__ bout,
                           float* __restrict__ out) {
    __shared__ float red[4][64];
    __shared__ float sh[64];
    __shared__ float logits[OUT_DIM];
    int g = blockIdx.x;
    int t = threadIdx.x, f = t & 63, w = t >> 6;
    int lo = 0, hi = N_NODES;
    while (lo < hi) { int m = (lo + hi) >> 1; if (batch[m] < g) lo = m + 1; else hi = m; }
    int start = lo;
    hi = N_NODES;
    while (lo < hi) { int m = (lo + hi) >> 1; if (batch[m] < g + 1) lo = m + 1; else hi = m; }
    int end = lo;
    float a = 0.f;
    for (int i = start + w; i < end; i += 4)
        a += xm[(size_t)i * 64 + f];
    red[w][f] = a;
    __syncthreads();
    if (w == 0) {
        float cnt = (float)((end - start) > 0 ? (end - start) : 1);
        sh[f] = (red[0][f] + red[1][f] + red[2][f] + red[3][f]) / cnt;
    }
    __syncthreads();
    if (t < OUT_DIM) {
        float l = bout[t];
        for (int k = 0; k < 64; ++k) l += sh[k] * Wout[k * OUT_DIM + t];
        logits[t] = l;
    }
    __syncthreads();
    if (t < OUT_DIM) {
        float m = logits[0];
        for (int k = 1; k < OUT_DIM; ++k) m = fmaxf(m, logits[k]);
        float ssum = 0.f;
        for (int k = 0; k < OUT_DIM; ++k) ssum += expf(logits[k] - m);
        out[(size_t)g * OUT_DIM + t] = expf(logits[t] - m) / ssum;
    }
}

extern "C" void kernel_launch(void* const* d_in, const int* in_sizes, int n_in,
                              void* d_out, int out_size, void* d_ws, size_t ws_size,
                              hipStream_t stream) {
    const float* X     = (const float*)d_in[0];
    const int*   Lind  = (const int*)d_in[1];
    const int*   ind0  = Lind;
    const int*   ind1  = Lind + N_EDGES;
    const float* vals  = (const float*)d_in[2];
    const int*   batch = (const int*)d_in[3];
    const float* W1    = (const float*)d_in[4];
    const float* b1    = (const float*)d_in[5];
    const float* W2    = (const float*)d_in[6];
    const float* b2    = (const float*)d_in[7];
    const float* W3    = (const float*)d_in[8];
    const float* b3    = (const float*)d_in[9];
    const float* Wout  = (const float*)d_in[10];
    const float* bout  = (const float*)d_in[11];
    float* out = (float*)d_out;

    // workspace layout (4B words)
    int* cnt0    = (int*)d_ws;                     // 50000
    int* cnt1    = cnt0 + 50000;                   // 50000
    unsigned int* c0pack = (unsigned int*)(cnt1 + 50000);  // 2,400,000 u32
    int*  c1src  = (int*)(c0pack + 50000 * CAP);   // 2,400,000
    uint2* G0bf  = (uint2*)(c1src + 50000 * CAP);  // 800,000 uint2
    uint2* G1bf  = G0bf + 800000;
    uint2* G2bf  = G1bf + 800000;
    uint2* Rbf   = G2bf + 800000;
    uint2* hbf   = Rbf + 800000;
    float* xm    = (float*)(hbf + 800000);         // 3,200,000 fp32
    // bf16 buffer reuse after producers die:
    uint2* x1bf  = G0bf;   // G0 dead after spmm1
    uint2* x2bf  = G1bf;   // G1 dead after spmm0

    const int B = 256;
    const int gatherGrid = 12500 * 64 / B;                // 3125 blocks (4 nodes/wave)
    const int tileGrid = GEMM_BLOCKS;                     // 782
    const int partGrid = NCHUNKS * 8;                     // 3128

    // direct CSR build (no hist / no scan)
    k_zero_int<<<(100000 + B - 1) / B, B, 0, stream>>>(cnt0, 100000);  // cnt0+cnt1 contiguous
    k_scatter_direct<<<partGrid, B, 0, stream>>>(ind0, ind1, vals, cnt0, cnt1, c0pack, c1src);

    // layer-1 GEMMs: G0/G1/G2 bf16
    k_gemm1x3<<<tileGrid, B, 0, stream>>>(X, W1, G0bf, G1bf, G2bf);

    // Chebyshev via linearity (64-dim spmms, bf16 gathers):
    // R = G1 + 2*(L@G2);  h1' = dis*(L@R + G0 - G2)
    k_spmm64v<0><<<gatherGrid, B, 0, stream>>>(cnt0, c0pack, G2bf, G1bf, nullptr, cnt1, Rbf);
    k_spmm64v<1><<<gatherGrid, B, 0, stream>>>(cnt0, c0pack, Rbf, G0bf, G2bf, cnt1, hbf);

    // layer 1 conv (writes x1bf into G0bf's space)
    k_conv_gatherv<0><<<gatherGrid, B, 0, stream>>>(cnt1, c1src, hbf, b1,
                                                    nullptr, nullptr, x1bf, nullptr);

    // layer 2: hbf = dis*(x1@W2), conv (x2bf into G1bf's space)
    k_gemm64<<<tileGrid, B, 0, stream>>>(x1bf, W2, cnt1, hbf);
    k_conv_gatherv<0><<<gatherGrid, B, 0, stream>>>(cnt1, c1src, hbf, b2,
                                                    nullptr, nullptr, x2bf, nullptr);

    // layer 3: conv writes xm = (x1+x2+x3)/3 (fp32)
    k_gemm64<<<tileGrid, B, 0, stream>>>(x2bf, W3, cnt1, hbf);
    k_conv_gatherv<1><<<gatherGrid, B, 0, stream>>>(cnt1, c1src, hbf, b3,
                                                    x1bf, x2bf, nullptr, (float4*)xm);

    // pool + head
    k_pool_out<<<N_GRAPHS, B, 0, stream>>>(xm, batch, Wout, bout, out);
}

// Round 21
// 277.756 us; speedup vs baseline: 1.1808x; 1.0623x over previous
//
#include <hip/hip_runtime.h>
#include <hip/hip_bf16.h>
#include <hip/hip_fp16.h>

#define N_NODES 50000
#define N_EDGES 800000
#define IN_DIM 128
#define F_SIZE 64
#define N_GRAPHS 512
#define OUT_DIM 10
#define EDGE_CHUNK 2048
#define NCHUNKS ((N_EDGES + EDGE_CHUNK - 1) / EDGE_CHUNK)   // 391
#define NODES_PER_XCD ((N_NODES + 7) / 8)                    // 6250
#define GEMM_BLOCKS 782        // ceil(50000/64)
#define CAP 48                 // per-node CSR bucket capacity (max degree ~45 @ Poisson(16))

// ---------------- bf16 pack/unpack helpers (round-to-nearest-even) ----------------
__device__ __forceinline__ unsigned int pack_bf2(float a, float b) {
    unsigned int ua = __float_as_uint(a);
    unsigned int ub = __float_as_uint(b);
    ua += 0x7fffu + ((ua >> 16) & 1u);
    ub += 0x7fffu + ((ub >> 16) & 1u);
    return (ua >> 16) | (ub & 0xffff0000u);
}
__device__ __forceinline__ uint2 pack_f4(float4 o) {
    return make_uint2(pack_bf2(o.x, o.y), pack_bf2(o.z, o.w));
}
__device__ __forceinline__ float4 unpack_f4(uint2 u) {
    float4 f;
    f.x = __uint_as_float(u.x << 16);
    f.y = __uint_as_float(u.x & 0xffff0000u);
    f.z = __uint_as_float(u.y << 16);
    f.w = __uint_as_float(u.y & 0xffff0000u);
    return f;
}

// ---------------- utility ----------------
__global__ void k_zero_int(int* __restrict__ p, int n) {
    int i = blockIdx.x * blockDim.x + threadIdx.x;
    if (i < n) p[i] = 0;
}

// ---------------- XCD-partitioned direct scatter ----------------
// c0 payload: one u32 = (col << 16) | fp16(val).  c1 payload: src node id (u32).
__global__ __launch_bounds__(256) void k_scatter_direct(const int* __restrict__ ind0,
                                                        const int* __restrict__ ind1,
                                                        const float* __restrict__ vals,
                                                        int* __restrict__ cnt0, int* __restrict__ cnt1,
                                                        unsigned int* __restrict__ c0pack,
                                                        int* __restrict__ c1src) {
    int xcd = blockIdx.x & 7;
    int chunk = blockIdx.x >> 3;
    int lo = xcd * NODES_PER_XCD, hi = lo + NODES_PER_XCD;
    int base = chunk * EDGE_CHUNK;
    int end = base + EDGE_CHUNK; if (end > N_EDGES) end = N_EDGES;
    for (int e = base + threadIdx.x; e < end; e += 256) {
        int r = ind0[e];
        int c = ind1[e];
        if (r >= lo && r < hi) {
            int p0 = atomicAdd(&cnt0[r], 1);
            unsigned int hv = (unsigned int)__half_as_ushort(__float2half(vals[e]));
            c0pack[r * CAP + p0] = ((unsigned int)c << 16) | hv;
        }
        if (c >= lo && c < hi) {
            int p1 = atomicAdd(&cnt1[c], 1);
            c1src[c * CAP + p1] = r;
        }
    }
}

// ---------------- layer-1 GEMM, one segment per block (grid = 3*782, BK=32) ----------------
// blk -> tile = blk/3, seg = blk%3 (consecutive blocks share the X tile -> L2-local).
// Fixes R20's grid starvation: 782 blocks -> 2346, LDS 33.8KB -> 16.9KB.
#define AT_STRIDE 68
__global__ __launch_bounds__(256) void k_gemm1seg(const float* __restrict__ X,
                                                  const float* __restrict__ W1,
                                                  uint2* __restrict__ G0bf,
                                                  uint2* __restrict__ G1bf,
                                                  uint2* __restrict__ G2bf) {
    __shared__ float At[32 * AT_STRIDE];
    __shared__ float Wl[32 * 64];
    const int blk = blockIdx.x;
    const int tile = blk / 3;
    const int sg = blk - tile * 3;
    const int t = threadIdx.x;
    const int l = t & 63, w = t >> 6;
    const int r0 = tile * 64;
    const int rbase = w * 16 + (l >> 4) * 4;
    const int cbase = (l & 15) * 4;
    float acc[4][4] = {};

    #pragma unroll
    for (int ch = 0; ch < 4; ++ch) {
        const int koff = ch * 32;
        // stage At: 64 rows x 32 k = 512 float4, 2/thread
        #pragma unroll
        for (int i = 0; i < 2; ++i) {
            int f   = i * 256 + t;
            int row = f >> 3;
            int kq  = f & 7;
            int gr  = r0 + row; if (gr > N_NODES - 1) gr = N_NODES - 1;
            float4 v = *(const float4*)(X + (size_t)gr * IN_DIM + koff + kq * 4);
            At[(kq * 4 + 0) * AT_STRIDE + row] = v.x;
            At[(kq * 4 + 1) * AT_STRIDE + row] = v.y;
            At[(kq * 4 + 2) * AT_STRIDE + row] = v.z;
            At[(kq * 4 + 3) * AT_STRIDE + row] = v.w;
        }
        // stage Wl: 32 x 64 floats = 512 float4, 2/thread
        {
            const float4* Wg = (const float4*)(W1 + ((size_t)sg * 128 + koff) * 64);
            float4 wtmp[2];
            #pragma unroll
            for (int i = 0; i < 2; ++i) wtmp[i] = Wg[i * 256 + t];
            __syncthreads();   // previous chunk's consumers done
            #pragma unroll
            for (int i = 0; i < 2; ++i) *(float4*)&Wl[(i * 256 + t) * 4] = wtmp[i];
            __syncthreads();
        }
        #pragma unroll 8
        for (int k = 0; k < 32; ++k) {
            float4 a4 = *(const float4*)&At[k * AT_STRIDE + rbase];
            float4 w4 = *(const float4*)&Wl[k * 64 + cbase];
            acc[0][0] += a4.x * w4.x; acc[0][1] += a4.x * w4.y; acc[0][2] += a4.x * w4.z; acc[0][3] += a4.x * w4.w;
            acc[1][0] += a4.y * w4.x; acc[1][1] += a4.y * w4.y; acc[1][2] += a4.y * w4.z; acc[1][3] += a4.y * w4.w;
            acc[2][0] += a4.z * w4.x; acc[2][1] += a4.z * w4.y; acc[2][2] += a4.z * w4.z; acc[2][3] += a4.z * w4.w;
            acc[3][0] += a4.w * w4.x; acc[3][1] += a4.w * w4.y; acc[3][2] += a4.w * w4.z; acc[3][3] += a4.w * w4.w;
        }
        __syncthreads();  // protect At/Wl restage
    }
    uint2* Gout = (sg == 0) ? G0bf : (sg == 1) ? G1bf : G2bf;
    #pragma unroll
    for (int r = 0; r < 4; ++r) {
        int gr = r0 + rbase + r;
        if (gr < N_NODES) {
            float4 o = {acc[r][0], acc[r][1], acc[r][2], acc[r][3]};
            Gout[(size_t)gr * 16 + (l & 15)] = pack_f4(o);
        }
    }
}

// ---------------- bf16-gather SpMM: wave = 4 nodes, 16 lanes/row ----------------
// MODE 0: Rbf = A(G1bf) + 2*acc(src=G2bf)
// MODE 1: hbf = dis*(acc(src=Rbf) + A(G0bf) - B(G2bf))
template<int MODE>
__global__ __launch_bounds__(256) void k_spmm64v(const int* __restrict__ cnt0,
                          const unsigned int* __restrict__ pack,
                          const uint2* __restrict__ srcbf, const uint2* __restrict__ Abf,
                          const uint2* __restrict__ Bbf, const int* __restrict__ cnt1,
                          uint2* __restrict__ dstbf) {
    int t = blockIdx.x * blockDim.x + threadIdx.x;
    int wid = t >> 6, lane = t & 63;
    int grp = lane >> 4, sub = lane & 15;
    int node = wid * 4 + grp;
    if (node >= N_NODES) return;
    int s = node * CAP;
    int e = s + cnt0[node];
    float4 acc = {0.f, 0.f, 0.f, 0.f};
    int j = s;
    for (; j + 3 < e; j += 4) {
        unsigned int p0 = pack[j], p1 = pack[j + 1], p2 = pack[j + 2], p3 = pack[j + 3];
        float4 r0 = unpack_f4(srcbf[(size_t)(p0 >> 16) * 16 + sub]);
        float4 r1 = unpack_f4(srcbf[(size_t)(p1 >> 16) * 16 + sub]);
        float4 r2 = unpack_f4(srcbf[(size_t)(p2 >> 16) * 16 + sub]);
        float4 r3 = unpack_f4(srcbf[(size_t)(p3 >> 16) * 16 + sub]);
        float v0 = __half2float(__ushort_as_half((unsigned short)(p0 & 0xffffu)));
        float v1 = __half2float(__ushort_as_half((unsigned short)(p1 & 0xffffu)));
        float v2 = __half2float(__ushort_as_half((unsigned short)(p2 & 0xffffu)));
        float v3 = __half2float(__ushort_as_half((unsigned short)(p3 & 0xffffu)));
        acc.x += v0 * r0.x + v1 * r1.x + v2 * r2.x + v3 * r3.x;
        acc.y += v0 * r0.y + v1 * r1.y + v2 * r2.y + v3 * r3.y;
        acc.z += v0 * r0.z + v1 * r1.z + v2 * r2.z + v3 * r3.z;
        acc.w += v0 * r0.w + v1 * r1.w + v2 * r2.w + v3 * r3.w;
    }
    for (; j < e; ++j) {
        unsigned int p = pack[j];
        float4 r = unpack_f4(srcbf[(size_t)(p >> 16) * 16 + sub]);
        float v = __half2float(__ushort_as_half((unsigned short)(p & 0xffffu)));
        acc.x += v * r.x; acc.y += v * r.y; acc.z += v * r.z; acc.w += v * r.w;
    }
    size_t idx = (size_t)node * 16 + sub;
    float4 a = unpack_f4(Abf[idx]);
    float4 o;
    if (MODE == 0) {
        o.x = a.x + 2.f * acc.x; o.y = a.y + 2.f * acc.y;
        o.z = a.z + 2.f * acc.z; o.w = a.w + 2.f * acc.w;
    } else {
        float4 bb = unpack_f4(Bbf[idx]);
        float d = rsqrtf(1.0f + (float)cnt1[node]);
        o.x = d * (acc.x + a.x - bb.x); o.y = d * (acc.y + a.y - bb.y);
        o.z = d * (acc.z + a.z - bb.z); o.w = d * (acc.w + a.w - bb.w);
    }
    dstbf[idx] = pack_f4(o);
}

// ---------------- bf16-gather conv ----------------
// FINAL=0: xbf = bf16(relu(dis*(acc + self) + b))
// FINAL=1: xm  = (x1 + x2 + relu(...))/3   (fp32, feeds pool only)
template<int FINAL>
__global__ void k_conv_gatherv(const int* __restrict__ cnt1, const int* __restrict__ csrc,
                               const uint2* __restrict__ hbf,
                               const float* __restrict__ b,
                               const uint2* __restrict__ x1bf, const uint2* __restrict__ x2bf,
                               uint2* __restrict__ outbf, float4* __restrict__ outf) {
    int t = blockIdx.x * blockDim.x + threadIdx.x;
    int wid = t >> 6, lane = t & 63;
    int grp = lane >> 4, sub = lane & 15;
    int node = wid * 4 + grp;
    if (node >= N_NODES) return;
    int deg = cnt1[node];
    int s = node * CAP;
    int e = s + deg;
    float4 acc = {0.f, 0.f, 0.f, 0.f};
    int j = s;
    for (; j + 3 < e; j += 4) {
        int s0 = csrc[j], s1 = csrc[j + 1], s2 = csrc[j + 2], s3 = csrc[j + 3];
        float4 r0 = unpack_f4(hbf[(size_t)s0 * 16 + sub]);
        float4 r1 = unpack_f4(hbf[(size_t)s1 * 16 + sub]);
        float4 r2 = unpack_f4(hbf[(size_t)s2 * 16 + sub]);
        float4 r3 = unpack_f4(hbf[(size_t)s3 * 16 + sub]);
        acc.x += (r0.x + r1.x) + (r2.x + r3.x);
        acc.y += (r0.y + r1.y) + (r2.y + r3.y);
        acc.z += (r0.z + r1.z) + (r2.z + r3.z);
        acc.w += (r0.w + r1.w) + (r2.w + r3.w);
    }
    for (; j < e; ++j) {
        float4 r = unpack_f4(hbf[(size_t)csrc[j] * 16 + sub]);
        acc.x += r.x; acc.y += r.y; acc.z += r.z; acc.w += r.w;
    }
    size_t idx = (size_t)node * 16 + sub;
    float4 sl = unpack_f4(hbf[idx]);      // self loop
    float d = rsqrtf(1.0f + (float)deg);
    float4 bv = ((const float4*)b)[sub];
    float4 o;
    o.x = fmaxf(d * (acc.x + sl.x) + bv.x, 0.f);
    o.y = fmaxf(d * (acc.y + sl.y) + bv.y, 0.f);
    o.z = fmaxf(d * (acc.z + sl.z) + bv.z, 0.f);
    o.w = fmaxf(d * (acc.w + sl.w) + bv.w, 0.f);
    if (FINAL) {
        float4 a1 = unpack_f4(x1bf[idx]), a2 = unpack_f4(x2bf[idx]);
        const float third = 1.f / 3.f;
        o.x = (a1.x + a2.x + o.x) * third;
        o.y = (a1.y + a2.y + o.y) * third;
        o.z = (a1.z + a2.z + o.z) * third;
        o.w = (a1.w + a2.w + o.w) * third;
        outf[idx] = o;
    } else {
        outbf[idx] = pack_f4(o);
    }
}

// ---------------- LDS-tiled GEMM: hbf = dis ⊙ (s0bf @ W), bf16 in/out ----------------
__global__ __launch_bounds__(256) void k_gemm64(const uint2* __restrict__ s0bf,
                                                const float* __restrict__ W,
                                                const int* __restrict__ cnt1,
                                                uint2* __restrict__ Cbf) {
    __shared__ float At[64 * AT_STRIDE];
    __shared__ float Wl[64 * 64];
    const int t = threadIdx.x;
    const int l = t & 63, w = t >> 6;
    const int r0 = blockIdx.x * 64;
    const int rbase = w * 16 + (l >> 4) * 4;
    const int cbase = (l & 15) * 4;
    float acc[4][4] = {};

    {
        const float4* Wg = (const float4*)W;
        #pragma unroll
        for (int i = 0; i < 4; ++i) *(float4*)&Wl[(i * 256 + t) * 4] = Wg[i * 256 + t];
    }
    #pragma unroll
    for (int i = 0; i < 4; ++i) {
        int f   = i * 256 + t;
        int row = f >> 4;
        int kq  = f & 15;
        int gr  = r0 + row; if (gr > N_NODES - 1) gr = N_NODES - 1;
        float4 v = unpack_f4(s0bf[(size_t)gr * 16 + kq]);
        At[(kq * 4 + 0) * AT_STRIDE + row] = v.x;
        At[(kq * 4 + 1) * AT_STRIDE + row] = v.y;
        At[(kq * 4 + 2) * AT_STRIDE + row] = v.z;
        At[(kq * 4 + 3) * AT_STRIDE + row] = v.w;
    }
    __syncthreads();
    #pragma unroll 8
    for (int k = 0; k < 64; ++k) {
        float4 a4 = *(const float4*)&At[k * AT_STRIDE + rbase];
        float4 w4 = *(const float4*)&Wl[k * 64 + cbase];
        acc[0][0] += a4.x * w4.x; acc[0][1] += a4.x * w4.y; acc[0][2] += a4.x * w4.z; acc[0][3] += a4.x * w4.w;
        acc[1][0] += a4.y * w4.x; acc[1][1] += a4.y * w4.y; acc[1][2] += a4.y * w4.z; acc[1][3] += a4.y * w4.w;
        acc[2][0] += a4.z * w4.x; acc[2][1] += a4.z * w4.y; acc[2][2] += a4.z * w4.z; acc[2][3] += a4.z * w4.w;
        acc[3][0] += a4.w * w4.x; acc[3][1] += a4.w * w4.y; acc[3][2] += a4.w * w4.z; acc[3][3] += a4.w * w4.w;
    }
    #pragma unroll
    for (int r = 0; r < 4; ++r) {
        int gr = r0 + rbase + r;
        if (gr < N_NODES) {
            float d = rsqrtf(1.0f + (float)cnt1[gr]);
            float4 o = {d * acc[r][0], d * acc[r][1], d * acc[r][2], d * acc[r][3]};
            Cbf[(size_t)gr * 16 + (l & 15)] = pack_f4(o);
        }
    }
}

// ---------------- pool (batch sorted -> contiguous ranges) + head, 4 waves ----------------
__global__ __launch_bounds__(256) void k_pool_out(const float* __restrict__ xm,
                           const int* __restrict__ batch,
                           const float* __restrict__ Wout, const float* __restrict__ bout,
                           float* __restrict__ out) {
    __shared__ float red[4][64];
    __shared__ float sh[64];
    __shared__ float logits[OUT_DIM];
    int g = blockIdx.x;
    int t = threadIdx.x, f = t & 63, w = t >> 6;
    int lo = 0, hi = N_NODES;
    while (lo < hi) { int m = (lo + hi) >> 1; if (batch[m] < g) lo = m + 1; else hi = m; }
    int start = lo;
    hi = N_NODES;
    while (lo < hi) { int m = (lo + hi) >> 1; if (batch[m] < g + 1) lo = m + 1; else hi = m; }
    int end = lo;
    float a = 0.f;
    for (int i = start + w; i < end; i += 4)
        a += xm[(size_t)i * 64 + f];
    red[w][f] = a;
    __syncthreads();
    if (w == 0) {
        float cnt = (float)((end - start) > 0 ? (end - start) : 1);
        sh[f] = (red[0][f] + red[1][f] + red[2][f] + red[3][f]) / cnt;
    }
    __syncthreads();
    if (t < OUT_DIM) {
        float l = bout[t];
        for (int k = 0; k < 64; ++k) l += sh[k] * Wout[k * OUT_DIM + t];
        logits[t] = l;
    }
    __syncthreads();
    if (t < OUT_DIM) {
        float m = logits[0];
        for (int k = 1; k < OUT_DIM; ++k) m = fmaxf(m, logits[k]);
        float ssum = 0.f;
        for (int k = 0; k < OUT_DIM; ++k) ssum += expf(logits[k] - m);
        out[(size_t)g * OUT_DIM + t] = expf(logits[t] - m) / ssum;
    }
}

extern "C" void kernel_launch(void* const* d_in, const int* in_sizes, int n_in,
                              void* d_out, int out_size, void* d_ws, size_t ws_size,
                              hipStream_t stream) {
    const float* X     = (const float*)d_in[0];
    const int*   Lind  = (const int*)d_in[1];
    const int*   ind0  = Lind;
    const int*   ind1  = Lind + N_EDGES;
    const float* vals  = (const float*)d_in[2];
    const int*   batch = (const int*)d_in[3];
    const float* W1    = (const float*)d_in[4];
    const float* b1    = (const float*)d_in[5];
    const float* W2    = (const float*)d_in[6];
    const float* b2    = (const float*)d_in[7];
    const float* W3    = (const float*)d_in[8];
    const float* b3    = (const float*)d_in[9];
    const float* Wout  = (const float*)d_in[10];
    const float* bout  = (const float*)d_in[11];
    float* out = (float*)d_out;

    // workspace layout (4B words)
    int* cnt0    = (int*)d_ws;                     // 50000
    int* cnt1    = cnt0 + 50000;                   // 50000
    unsigned int* c0pack = (unsigned int*)(cnt1 + 50000);  // 2,400,000 u32
    int*  c1src  = (int*)(c0pack + 50000 * CAP);   // 2,400,000
    uint2* G0bf  = (uint2*)(c1src + 50000 * CAP);  // 800,000 uint2
    uint2* G1bf  = G0bf + 800000;
    uint2* G2bf  = G1bf + 800000;
    uint2* Rbf   = G2bf + 800000;
    uint2* hbf   = Rbf + 800000;
    float* xm    = (float*)(hbf + 800000);         // 3,200,000 fp32
    // bf16 buffer reuse after producers die:
    uint2* x1bf  = G0bf;   // G0 dead after spmm1
    uint2* x2bf  = G1bf;   // G1 dead after spmm0

    const int B = 256;
    const int gatherGrid = 12500 * 64 / B;                // 3125 blocks (4 nodes/wave)
    const int tileGrid = GEMM_BLOCKS;                     // 782
    const int partGrid = NCHUNKS * 8;                     // 3128

    // direct CSR build (no hist / no scan)
    k_zero_int<<<(100000 + B - 1) / B, B, 0, stream>>>(cnt0, 100000);  // cnt0+cnt1 contiguous
    k_scatter_direct<<<partGrid, B, 0, stream>>>(ind0, ind1, vals, cnt0, cnt1, c0pack, c1src);

    // layer-1 GEMMs: one segment per block (3x grid vs R20, BK=32)
    k_gemm1seg<<<tileGrid * 3, B, 0, stream>>>(X, W1, G0bf, G1bf, G2bf);

    // Chebyshev via linearity (64-dim spmms, bf16 gathers):
    // R = G1 + 2*(L@G2);  h1' = dis*(L@R + G0 - G2)
    k_spmm64v<0><<<gatherGrid, B, 0, stream>>>(cnt0, c0pack, G2bf, G1bf, nullptr, cnt1, Rbf);
    k_spmm64v<1><<<gatherGrid, B, 0, stream>>>(cnt0, c0pack, Rbf, G0bf, G2bf, cnt1, hbf);

    // layer 1 conv (writes x1bf into G0bf's space)
    k_conv_gatherv<0><<<gatherGrid, B, 0, stream>>>(cnt1, c1src, hbf, b1,
                                                    nullptr, nullptr, x1bf, nullptr);

    // layer 2: hbf = dis*(x1@W2), conv (x2bf into G1bf's space)
    k_gemm64<<<tileGrid, B, 0, stream>>>(x1bf, W2, cnt1, hbf);
    k_conv_gatherv<0><<<gatherGrid, B, 0, stream>>>(cnt1, c1src, hbf, b2,
                                                    nullptr, nullptr, x2bf, nullptr);

    // layer 3: conv writes xm = (x1+x2+x3)/3 (fp32)
    k_gemm64<<<tileGrid, B, 0, stream>>>(x2bf, W3, cnt1, hbf);
    k_conv_gatherv<1><<<gatherGrid, B, 0, stream>>>(cnt1, c1src, hbf, b3,
                                                    x1bf, x2bf, nullptr, (float4*)xm);

    // pool + head
    k_pool_out<<<N_GRAPHS, B, 0, stream>>>(xm, batch, Wout, bout, out);
}

// Round 22
// 259.405 us; speedup vs baseline: 1.2644x; 1.0707x over previous
//
#include <hip/hip_runtime.h>
#include <hip/hip_bf16.h>
#include <hip/hip_fp16.h>

#define N_NODES 50000
#define N_EDGES 800000
#define IN_DIM 128
#define F_SIZE 64
#define N_GRAPHS 512
#define OUT_DIM 10
#define EDGE_CHUNK 2048
#define NCHUNKS ((N_EDGES + EDGE_CHUNK - 1) / EDGE_CHUNK)   // 391
#define NODES_PER_XCD ((N_NODES + 7) / 8)                    // 6250
#define GEMM_BLOCKS 782        // ceil(50000/64)
#define CAP 48                 // per-node CSR bucket capacity (max degree ~45 @ Poisson(16))

// ---------------- bf16 pack/unpack helpers (round-to-nearest-even) ----------------
__device__ __forceinline__ unsigned int pack_bf2(float a, float b) {
    unsigned int ua = __float_as_uint(a);
    unsigned int ub = __float_as_uint(b);
    ua += 0x7fffu + ((ua >> 16) & 1u);
    ub += 0x7fffu + ((ub >> 16) & 1u);
    return (ua >> 16) | (ub & 0xffff0000u);
}
__device__ __forceinline__ uint2 pack_f4(float4 o) {
    return make_uint2(pack_bf2(o.x, o.y), pack_bf2(o.z, o.w));
}
__device__ __forceinline__ float4 unpack_f4(uint2 u) {
    float4 f;
    f.x = __uint_as_float(u.x << 16);
    f.y = __uint_as_float(u.x & 0xffff0000u);
    f.z = __uint_as_float(u.y << 16);
    f.w = __uint_as_float(u.y & 0xffff0000u);
    return f;
}

// ---------------- utility ----------------
__global__ void k_zero_int(int* __restrict__ p, int n) {
    int i = blockIdx.x * blockDim.x + threadIdx.x;
    if (i < n) p[i] = 0;
}

// ---------------- XCD-partitioned direct scatter ----------------
__global__ __launch_bounds__(256) void k_scatter_direct(const int* __restrict__ ind0,
                                                        const int* __restrict__ ind1,
                                                        const float* __restrict__ vals,
                                                        int* __restrict__ cnt0, int* __restrict__ cnt1,
                                                        unsigned int* __restrict__ c0pack,
                                                        int* __restrict__ c1src) {
    int xcd = blockIdx.x & 7;
    int chunk = blockIdx.x >> 3;
    int lo = xcd * NODES_PER_XCD, hi = lo + NODES_PER_XCD;
    int base = chunk * EDGE_CHUNK;
    int end = base + EDGE_CHUNK; if (end > N_EDGES) end = N_EDGES;
    for (int e = base + threadIdx.x; e < end; e += 256) {
        int r = ind0[e];
        int c = ind1[e];
        if (r >= lo && r < hi) {
            int p0 = atomicAdd(&cnt0[r], 1);
            unsigned int hv = (unsigned int)__half_as_ushort(__float2half(vals[e]));
            c0pack[r * CAP + p0] = ((unsigned int)c << 16) | hv;
        }
        if (c >= lo && c < hi) {
            int p1 = atomicAdd(&cnt1[c], 1);
            c1src[c * CAP + p1] = r;
        }
    }
}

// ---------------- layer-1 GEMM, one segment per block (grid = 3*782, BK=32) ----------------
#define AT_STRIDE 68
__global__ __launch_bounds__(256) void k_gemm1seg(const float* __restrict__ X,
                                                  const float* __restrict__ W1,
                                                  uint2* __restrict__ G0bf,
                                                  uint2* __restrict__ G1bf,
                                                  uint2* __restrict__ G2bf) {
    __shared__ float At[32 * AT_STRIDE];
    __shared__ float Wl[32 * 64];
    const int blk = blockIdx.x;
    const int tile = blk / 3;
    const int sg = blk - tile * 3;
    const int t = threadIdx.x;
    const int l = t & 63, w = t >> 6;
    const int r0 = tile * 64;
    const int rbase = w * 16 + (l >> 4) * 4;
    const int cbase = (l & 15) * 4;
    float acc[4][4] = {};

    #pragma unroll
    for (int ch = 0; ch < 4; ++ch) {
        const int koff = ch * 32;
        #pragma unroll
        for (int i = 0; i < 2; ++i) {
            int f   = i * 256 + t;
            int row = f >> 3;
            int kq  = f & 7;
            int gr  = r0 + row; if (gr > N_NODES - 1) gr = N_NODES - 1;
            float4 v = *(const float4*)(X + (size_t)gr * IN_DIM + koff + kq * 4);
            At[(kq * 4 + 0) * AT_STRIDE + row] = v.x;
            At[(kq * 4 + 1) * AT_STRIDE + row] = v.y;
            At[(kq * 4 + 2) * AT_STRIDE + row] = v.z;
            At[(kq * 4 + 3) * AT_STRIDE + row] = v.w;
        }
        {
            const float4* Wg = (const float4*)(W1 + ((size_t)sg * 128 + koff) * 64);
            float4 wtmp[2];
            #pragma unroll
            for (int i = 0; i < 2; ++i) wtmp[i] = Wg[i * 256 + t];
            __syncthreads();
            #pragma unroll
            for (int i = 0; i < 2; ++i) *(float4*)&Wl[(i * 256 + t) * 4] = wtmp[i];
            __syncthreads();
        }
        #pragma unroll 8
        for (int k = 0; k < 32; ++k) {
            float4 a4 = *(const float4*)&At[k * AT_STRIDE + rbase];
            float4 w4 = *(const float4*)&Wl[k * 64 + cbase];
            acc[0][0] += a4.x * w4.x; acc[0][1] += a4.x * w4.y; acc[0][2] += a4.x * w4.z; acc[0][3] += a4.x * w4.w;
            acc[1][0] += a4.y * w4.x; acc[1][1] += a4.y * w4.y; acc[1][2] += a4.y * w4.z; acc[1][3] += a4.y * w4.w;
            acc[2][0] += a4.z * w4.x; acc[2][1] += a4.z * w4.y; acc[2][2] += a4.z * w4.z; acc[2][3] += a4.z * w4.w;
            acc[3][0] += a4.w * w4.x; acc[3][1] += a4.w * w4.y; acc[3][2] += a4.w * w4.z; acc[3][3] += a4.w * w4.w;
        }
        __syncthreads();
    }
    uint2* Gout = (sg == 0) ? G0bf : (sg == 1) ? G1bf : G2bf;
    #pragma unroll
    for (int r = 0; r < 4; ++r) {
        int gr = r0 + rbase + r;
        if (gr < N_NODES) {
            float4 o = {acc[r][0], acc[r][1], acc[r][2], acc[r][3]};
            Gout[(size_t)gr * 16 + (l & 15)] = pack_f4(o);
        }
    }
}

// ---------------- bf16-gather SpMM: wave = 4 nodes, 16 lanes/row ----------------
// MODE 0: Rbf = A(G1bf) + 2*acc(src=G2bf)
// MODE 1: hbf = dis*(acc(src=Rbf) + A(G0bf) - B(G2bf))
template<int MODE>
__global__ __launch_bounds__(256) void k_spmm64v(const int* __restrict__ cnt0,
                          const unsigned int* __restrict__ pack,
                          const uint2* __restrict__ srcbf, const uint2* __restrict__ Abf,
                          const uint2* __restrict__ Bbf, const int* __restrict__ cnt1,
                          uint2* __restrict__ dstbf) {
    int t = blockIdx.x * blockDim.x + threadIdx.x;
    int wid = t >> 6, lane = t & 63;
    int grp = lane >> 4, sub = lane & 15;
    int node = wid * 4 + grp;
    if (node >= N_NODES) return;
    int s = node * CAP;
    int e = s + cnt0[node];
    float4 acc = {0.f, 0.f, 0.f, 0.f};
    int j = s;
    for (; j + 3 < e; j += 4) {
        unsigned int p0 = pack[j], p1 = pack[j + 1], p2 = pack[j + 2], p3 = pack[j + 3];
        float4 r0 = unpack_f4(srcbf[(size_t)(p0 >> 16) * 16 + sub]);
        float4 r1 = unpack_f4(srcbf[(size_t)(p1 >> 16) * 16 + sub]);
        float4 r2 = unpack_f4(srcbf[(size_t)(p2 >> 16) * 16 + sub]);
        float4 r3 = unpack_f4(srcbf[(size_t)(p3 >> 16) * 16 + sub]);
        float v0 = __half2float(__ushort_as_half((unsigned short)(p0 & 0xffffu)));
        float v1 = __half2float(__ushort_as_half((unsigned short)(p1 & 0xffffu)));
        float v2 = __half2float(__ushort_as_half((unsigned short)(p2 & 0xffffu)));
        float v3 = __half2float(__ushort_as_half((unsigned short)(p3 & 0xffffu)));
        acc.x += v0 * r0.x + v1 * r1.x + v2 * r2.x + v3 * r3.x;
        acc.y += v0 * r0.y + v1 * r1.y + v2 * r2.y + v3 * r3.y;
        acc.z += v0 * r0.z + v1 * r1.z + v2 * r2.z + v3 * r3.z;
        acc.w += v0 * r0.w + v1 * r1.w + v2 * r2.w + v3 * r3.w;
    }
    for (; j < e; ++j) {
        unsigned int p = pack[j];
        float4 r = unpack_f4(srcbf[(size_t)(p >> 16) * 16 + sub]);
        float v = __half2float(__ushort_as_half((unsigned short)(p & 0xffffu)));
        acc.x += v * r.x; acc.y += v * r.y; acc.z += v * r.z; acc.w += v * r.w;
    }
    size_t idx = (size_t)node * 16 + sub;
    float4 a = unpack_f4(Abf[idx]);
    float4 o;
    if (MODE == 0) {
        o.x = a.x + 2.f * acc.x; o.y = a.y + 2.f * acc.y;
        o.z = a.z + 2.f * acc.z; o.w = a.w + 2.f * acc.w;
    } else {
        float4 bb = unpack_f4(Bbf[idx]);
        float d = rsqrtf(1.0f + (float)cnt1[node]);
        o.x = d * (acc.x + a.x - bb.x); o.y = d * (acc.y + a.y - bb.y);
        o.z = d * (acc.z + a.z - bb.z); o.w = d * (acc.w + a.w - bb.w);
    }
    dstbf[idx] = pack_f4(o);
}

// ---------------- fused conv + 64x64 GEMM: block = 16 nodes ----------------
// conv: x = relu(dis*(gather-sum + self) + b)  -> xout (bf16, needed later)
// gemm: hout[node] = dis[node] * (x[node] @ W)  (ping-pong output buffer: no race
// with other blocks still gathering from hin)
__global__ __launch_bounds__(256) void k_conv_gemm(const int* __restrict__ cnt1,
                                                   const int* __restrict__ csrc,
                                                   const uint2* __restrict__ hin,
                                                   const float* __restrict__ b,
                                                   const float* __restrict__ W,
                                                   uint2* __restrict__ xout,
                                                   uint2* __restrict__ hout) {
    __shared__ float xl[16][64];
    __shared__ float4 Wl4[64 * 16];   // Wl4[k*16 + c4] = W[k][c4*4..c4*4+3]
    int t = threadIdx.x;
    int gt = blockIdx.x * 256 + t;
    int wid = gt >> 6, lane = t & 63;
    int grp = lane >> 4, sub = lane & 15;
    int node = wid * 4 + grp;                 // 3125 blocks * 16 = 50000 exactly
    int ln = ((t >> 6) << 2) + grp;           // local node 0..15
    int deg = cnt1[node];
    int s = node * CAP;
    int e = s + deg;
    float4 acc = {0.f, 0.f, 0.f, 0.f};
    int j = s;
    for (; j + 3 < e; j += 4) {
        int s0 = csrc[j], s1 = csrc[j + 1], s2 = csrc[j + 2], s3 = csrc[j + 3];
        float4 r0 = unpack_f4(hin[(size_t)s0 * 16 + sub]);
        float4 r1 = unpack_f4(hin[(size_t)s1 * 16 + sub]);
        float4 r2 = unpack_f4(hin[(size_t)s2 * 16 + sub]);
        float4 r3 = unpack_f4(hin[(size_t)s3 * 16 + sub]);
        acc.x += (r0.x + r1.x) + (r2.x + r3.x);
        acc.y += (r0.y + r1.y) + (r2.y + r3.y);
        acc.z += (r0.z + r1.z) + (r2.z + r3.z);
        acc.w += (r0.w + r1.w) + (r2.w + r3.w);
    }
    for (; j < e; ++j) {
        float4 r = unpack_f4(hin[(size_t)csrc[j] * 16 + sub]);
        acc.x += r.x; acc.y += r.y; acc.z += r.z; acc.w += r.w;
    }
    size_t idx = (size_t)node * 16 + sub;
    float4 sl = unpack_f4(hin[idx]);
    float d = rsqrtf(1.0f + (float)deg);
    float4 bv = ((const float4*)b)[sub];
    float4 o;
    o.x = fmaxf(d * (acc.x + sl.x) + bv.x, 0.f);
    o.y = fmaxf(d * (acc.y + sl.y) + bv.y, 0.f);
    o.z = fmaxf(d * (acc.z + sl.z) + bv.z, 0.f);
    o.w = fmaxf(d * (acc.w + sl.w) + bv.w, 0.f);
    xout[idx] = pack_f4(o);
    xl[ln][sub * 4 + 0] = o.x;
    xl[ln][sub * 4 + 1] = o.y;
    xl[ln][sub * 4 + 2] = o.z;
    xl[ln][sub * 4 + 3] = o.w;
    // stage W (64x64 fp32 = 1024 float4), 4 per thread
    {
        const float4* Wg = (const float4*)W;
        #pragma unroll
        for (int i = 0; i < 4; ++i) Wl4[i * 256 + t] = Wg[i * 256 + t];
    }
    __syncthreads();
    // gemm: thread -> (node n = t>>4, col-quad c4 = t&15)
    int n = t >> 4, c4 = t & 15;
    float4 h4 = {0.f, 0.f, 0.f, 0.f};
    #pragma unroll 8
    for (int k = 0; k < 64; ++k) {
        float xv = xl[n][k];
        float4 w4 = Wl4[k * 16 + c4];
        h4.x += xv * w4.x; h4.y += xv * w4.y; h4.z += xv * w4.z; h4.w += xv * w4.w;
    }
    int gnode = blockIdx.x * 16 + n;
    float dn = rsqrtf(1.0f + (float)cnt1[gnode]);
    h4.x *= dn; h4.y *= dn; h4.z *= dn; h4.w *= dn;
    hout[(size_t)gnode * 16 + c4] = pack_f4(h4);
}

// ---------------- final conv: xm = (x1 + x2 + relu(...))/3  (fp32, feeds pool) ----------------
__global__ void k_conv_final(const int* __restrict__ cnt1, const int* __restrict__ csrc,
                             const uint2* __restrict__ hin,
                             const float* __restrict__ b,
                             const uint2* __restrict__ x1bf, const uint2* __restrict__ x2bf,
                             float4* __restrict__ outf) {
    int t = blockIdx.x * blockDim.x + threadIdx.x;
    int wid = t >> 6, lane = t & 63;
    int grp = lane >> 4, sub = lane & 15;
    int node = wid * 4 + grp;
    if (node >= N_NODES) return;
    int deg = cnt1[node];
    int s = node * CAP;
    int e = s + deg;
    float4 acc = {0.f, 0.f, 0.f, 0.f};
    int j = s;
    for (; j + 3 < e; j += 4) {
        int s0 = csrc[j], s1 = csrc[j + 1], s2 = csrc[j + 2], s3 = csrc[j + 3];
        float4 r0 = unpack_f4(hin[(size_t)s0 * 16 + sub]);
        float4 r1 = unpack_f4(hin[(size_t)s1 * 16 + sub]);
        float4 r2 = unpack_f4(hin[(size_t)s2 * 16 + sub]);
        float4 r3 = unpack_f4(hin[(size_t)s3 * 16 + sub]);
        acc.x += (r0.x + r1.x) + (r2.x + r3.x);
        acc.y += (r0.y + r1.y) + (r2.y + r3.y);
        acc.z += (r0.z + r1.z) + (r2.z + r3.z);
        acc.w += (r0.w + r1.w) + (r2.w + r3.w);
    }
    for (; j < e; ++j) {
        float4 r = unpack_f4(hin[(size_t)csrc[j] * 16 + sub]);
        acc.x += r.x; acc.y += r.y; acc.z += r.z; acc.w += r.w;
    }
    size_t idx = (size_t)node * 16 + sub;
    float4 sl = unpack_f4(hin[idx]);
    float d = rsqrtf(1.0f + (float)deg);
    float4 bv = ((const float4*)b)[sub];
    float4 o;
    o.x = fmaxf(d * (acc.x + sl.x) + bv.x, 0.f);
    o.y = fmaxf(d * (acc.y + sl.y) + bv.y, 0.f);
    o.z = fmaxf(d * (acc.z + sl.z) + bv.z, 0.f);
    o.w = fmaxf(d * (acc.w + sl.w) + bv.w, 0.f);
    float4 a1 = unpack_f4(x1bf[idx]), a2 = unpack_f4(x2bf[idx]);
    const float third = 1.f / 3.f;
    o.x = (a1.x + a2.x + o.x) * third;
    o.y = (a1.y + a2.y + o.y) * third;
    o.z = (a1.z + a2.z + o.z) * third;
    o.w = (a1.w + a2.w + o.w) * third;
    outf[idx] = o;
}

// ---------------- pool (batch sorted -> contiguous ranges) + head, 4 waves ----------------
__global__ __launch_bounds__(256) void k_pool_out(const float* __restrict__ xm,
                           const int* __restrict__ batch,
                           const float* __restrict__ Wout, const float* __restrict__ bout,
                           float* __restrict__ out) {
    __shared__ float red[4][64];
    __shared__ float sh[64];
    __shared__ float logits[OUT_DIM];
    int g = blockIdx.x;
    int t = threadIdx.x, f = t & 63, w = t >> 6;
    int lo = 0, hi = N_NODES;
    while (lo < hi) { int m = (lo + hi) >> 1; if (batch[m] < g) lo = m + 1; else hi = m; }
    int start = lo;
    hi = N_NODES;
    while (lo < hi) { int m = (lo + hi) >> 1; if (batch[m] < g + 1) lo = m + 1; else hi = m; }
    int end = lo;
    float a = 0.f;
    for (int i = start + w; i < end; i += 4)
        a += xm[(size_t)i * 64 + f];
    red[w][f] = a;
    __syncthreads();
    if (w == 0) {
        float cnt = (float)((end - start) > 0 ? (end - start) : 1);
        sh[f] = (red[0][f] + red[1][f] + red[2][f] + red[3][f]) / cnt;
    }
    __syncthreads();
    if (t < OUT_DIM) {
        float l = bout[t];
        for (int k = 0; k < 64; ++k) l += sh[k] * Wout[k * OUT_DIM + t];
        logits[t] = l;
    }
    __syncthreads();
    if (t < OUT_DIM) {
        float m = logits[0];
        for (int k = 1; k < OUT_DIM; ++k) m = fmaxf(m, logits[k]);
        float ssum = 0.f;
        for (int k = 0; k < OUT_DIM; ++k) ssum += expf(logits[k] - m);
        out[(size_t)g * OUT_DIM + t] = expf(logits[t] - m) / ssum;
    }
}

extern "C" void kernel_launch(void* const* d_in, const int* in_sizes, int n_in,
                              void* d_out, int out_size, void* d_ws, size_t ws_size,
                              hipStream_t stream) {
    const float* X     = (const float*)d_in[0];
    const int*   Lind  = (const int*)d_in[1];
    const int*   ind0  = Lind;
    const int*   ind1  = Lind + N_EDGES;
    const float* vals  = (const float*)d_in[2];
    const int*   batch = (const int*)d_in[3];
    const float* W1    = (const float*)d_in[4];
    const float* b1    = (const float*)d_in[5];
    const float* W2    = (const float*)d_in[6];
    const float* b2    = (const float*)d_in[7];
    const float* W3    = (const float*)d_in[8];
    const float* b3    = (const float*)d_in[9];
    const float* Wout  = (const float*)d_in[10];
    const float* bout  = (const float*)d_in[11];
    float* out = (float*)d_out;

    // workspace layout (4B words)
    int* cnt0    = (int*)d_ws;                     // 50000
    int* cnt1    = cnt0 + 50000;                   // 50000
    unsigned int* c0pack = (unsigned int*)(cnt1 + 50000);  // 2,400,000 u32
    int*  c1src  = (int*)(c0pack + 50000 * CAP);   // 2,400,000
    uint2* G0bf  = (uint2*)(c1src + 50000 * CAP);  // 800,000 uint2
    uint2* G1bf  = G0bf + 800000;
    uint2* G2bf  = G1bf + 800000;
    uint2* Rbf   = G2bf + 800000;
    uint2* hbf   = Rbf + 800000;
    uint2* h2bf  = hbf + 800000;                   // ping-pong partner for fused conv+gemm
    float* xm    = (float*)(h2bf + 800000);        // 3,200,000 fp32
    // bf16 buffer reuse after producers die:
    uint2* x1bf  = G0bf;   // G0 dead after spmm1
    uint2* x2bf  = G1bf;   // G1 dead after spmm0

    const int B = 256;
    const int gatherGrid = 12500 * 64 / B;                // 3125 blocks (4 nodes/wave)
    const int partGrid = NCHUNKS * 8;                     // 3128

    // direct CSR build (no hist / no scan)
    k_zero_int<<<(100000 + B - 1) / B, B, 0, stream>>>(cnt0, 100000);  // cnt0+cnt1 contiguous
    k_scatter_direct<<<partGrid, B, 0, stream>>>(ind0, ind1, vals, cnt0, cnt1, c0pack, c1src);

    // layer-1 GEMMs: one segment per block (3x grid, BK=32)
    k_gemm1seg<<<GEMM_BLOCKS * 3, B, 0, stream>>>(X, W1, G0bf, G1bf, G2bf);

    // Chebyshev via linearity (64-dim spmms, bf16 gathers):
    // R = G1 + 2*(L@G2);  h1' = dis*(L@R + G0 - G2)
    k_spmm64v<0><<<gatherGrid, B, 0, stream>>>(cnt0, c0pack, G2bf, G1bf, nullptr, cnt1, Rbf);
    k_spmm64v<1><<<gatherGrid, B, 0, stream>>>(cnt0, c0pack, Rbf, G0bf, G2bf, cnt1, hbf);

    // layer 1 conv + layer-2 GEMM fused: reads hbf, writes x1bf + h2bf
    k_conv_gemm<<<gatherGrid, B, 0, stream>>>(cnt1, c1src, hbf, b1, W2, x1bf, h2bf);

    // layer 2 conv + layer-3 GEMM fused: reads h2bf, writes x2bf + hbf
    k_conv_gemm<<<gatherGrid, B, 0, stream>>>(cnt1, c1src, h2bf, b2, W3, x2bf, hbf);

    // layer 3 conv (final): reads hbf, writes xm = (x1+x2+x3)/3
    k_conv_final<<<gatherGrid, B, 0, stream>>>(cnt1, c1src, hbf, b3, x1bf, x2bf, (float4*)xm);

    // pool + head
    k_pool_out<<<N_GRAPHS, B, 0, stream>>>(xm, batch, Wout, bout, out);
}

// Round 23
// 241.428 us; speedup vs baseline: 1.3585x; 1.0745x over previous
//
#include <hip/hip_runtime.h>
#include <hip/hip_bf16.h>
#include <hip/hip_fp16.h>

#define N_NODES 50000
#define N_EDGES 800000
#define IN_DIM 128
#define F_SIZE 64
#define N_GRAPHS 512
#define OUT_DIM 10
#define EDGE_CHUNK 2048
#define NCHUNKS ((N_EDGES + EDGE_CHUNK - 1) / EDGE_CHUNK)   // 391
#define GEMM_BLOCKS 782        // ceil(50000/64)
#define CAP 48                 // per-node CSR bucket capacity (max degree ~45 @ Poisson(16))
#define NRANGE 196             // node ranges of 256 (50000 >> 8 -> 0..195)
#define SEGCAP 4608            // entries per range segment (mean 4096, +8 sigma)

// ---------------- bf16 pack/unpack helpers (round-to-nearest-even) ----------------
__device__ __forceinline__ unsigned int pack_bf2(float a, float b) {
    unsigned int ua = __float_as_uint(a);
    unsigned int ub = __float_as_uint(b);
    ua += 0x7fffu + ((ua >> 16) & 1u);
    ub += 0x7fffu + ((ub >> 16) & 1u);
    return (ua >> 16) | (ub & 0xffff0000u);
}
__device__ __forceinline__ uint2 pack_f4(float4 o) {
    return make_uint2(pack_bf2(o.x, o.y), pack_bf2(o.z, o.w));
}
__device__ __forceinline__ float4 unpack_f4(uint2 u) {
    float4 f;
    f.x = __uint_as_float(u.x << 16);
    f.y = __uint_as_float(u.x & 0xffff0000u);
    f.z = __uint_as_float(u.y << 16);
    f.w = __uint_as_float(u.y & 0xffff0000u);
    return f;
}

// ---------------- utility ----------------
__global__ void k_zero_int(int* __restrict__ p, int n) {
    int i = blockIdx.x * blockDim.x + threadIdx.x;
    if (i < n) p[i] = 0;
}

// ---------------- Phase A: bin edges by node-range (one edge read, LDS hist) ----------------
// c0 side keyed by r: seg entry uint2{ (rlow<<16)|fp16val, c }
// c1 side keyed by c: seg entry u32 = (clow<<16) | r   (r < 65536)
__global__ __launch_bounds__(256) void k_binA(const int* __restrict__ ind0,
                                              const int* __restrict__ ind1,
                                              const float* __restrict__ vals,
                                              int* __restrict__ gcur,
                                              uint2* __restrict__ c0seg,
                                              unsigned int* __restrict__ c1seg) {
    __shared__ int h0[NRANGE], h1[NRANGE], b0[NRANGE], b1[NRANGE];
    int t = threadIdx.x;
    if (t < NRANGE) { h0[t] = 0; h1[t] = 0; }
    __syncthreads();
    int base = blockIdx.x * EDGE_CHUNK;
    int r[8], c[8]; unsigned int hv[8];
    #pragma unroll
    for (int i = 0; i < 8; ++i) {
        int e = base + i * 256 + t;
        if (e < N_EDGES) {
            r[i] = ind0[e]; c[i] = ind1[e];
            hv[i] = (unsigned int)__half_as_ushort(__float2half(vals[e]));
            atomicAdd(&h0[r[i] >> 8], 1);
            atomicAdd(&h1[c[i] >> 8], 1);
        } else r[i] = -1;
    }
    __syncthreads();
    if (t < NRANGE) {
        b0[t] = atomicAdd(&gcur[t], h0[t]);
        b1[t] = atomicAdd(&gcur[NRANGE + t], h1[t]);
        h0[t] = 0; h1[t] = 0;
    }
    __syncthreads();
    #pragma unroll
    for (int i = 0; i < 8; ++i) {
        if (r[i] >= 0) {
            int bin0 = r[i] >> 8;
            int off0 = b0[bin0] + atomicAdd(&h0[bin0], 1);
            c0seg[(size_t)bin0 * SEGCAP + off0] =
                make_uint2(((unsigned int)(r[i] & 255) << 16) | hv[i], (unsigned int)c[i]);
            int bin1 = c[i] >> 8;
            int off1 = b1[bin1] + atomicAdd(&h1[bin1], 1);
            c1seg[(size_t)bin1 * SEGCAP + off1] =
                ((unsigned int)(c[i] & 255) << 16) | (unsigned int)r[i];
        }
    }
}

// ---------------- Phase B: per-range counting build (LDS cursors, no global atomics) ----------------
// block = (range, side); bucket region per range (49KB) is L2-resident -> 1 writeback/line.
__global__ __launch_bounds__(256) void k_binB(const int* __restrict__ gcur,
                                              const uint2* __restrict__ c0seg,
                                              const unsigned int* __restrict__ c1seg,
                                              unsigned int* __restrict__ c0pack,
                                              int* __restrict__ c1src,
                                              int* __restrict__ cnt0,
                                              int* __restrict__ cnt1) {
    __shared__ int cur[256];
    int t = threadIdx.x;
    int range = blockIdx.x >> 1;
    int side = blockIdx.x & 1;
    cur[t] = 0;
    __syncthreads();
    int nodeBase = range << 8;
    if (side == 0) {
        int n = gcur[range];
        for (int i = t; i < n; i += 256) {
            uint2 en = c0seg[(size_t)range * SEGCAP + i];
            int rlow = en.x >> 16;
            int node = nodeBase + rlow;
            int k = atomicAdd(&cur[rlow], 1);
            c0pack[(size_t)node * CAP + k] = (en.y << 16) | (en.x & 0xffffu);
        }
        __syncthreads();
        int node = nodeBase + t;
        if (node < N_NODES) cnt0[node] = cur[t];
    } else {
        int n = gcur[NRANGE + range];
        for (int i = t; i < n; i += 256) {
            unsigned int en = c1seg[(size_t)range * SEGCAP + i];
            int clow = (en >> 16) & 0xff;
            int node = nodeBase + clow;
            int k = atomicAdd(&cur[clow], 1);
            c1src[(size_t)node * CAP + k] = (int)(en & 0xffffu);
        }
        __syncthreads();
        int node = nodeBase + t;
        if (node < N_NODES) cnt1[node] = cur[t];
    }
}

// ---------------- layer-1 GEMM, one segment per block (grid = 3*782, BK=32) ----------------
#define AT_STRIDE 68
__global__ __launch_bounds__(256) void k_gemm1seg(const float* __restrict__ X,
                                                  const float* __restrict__ W1,
                                                  uint2* __restrict__ G0bf,
                                                  uint2* __restrict__ G1bf,
                                                  uint2* __restrict__ G2bf) {
    __shared__ float At[32 * AT_STRIDE];
    __shared__ float Wl[32 * 64];
    const int blk = blockIdx.x;
    const int tile = blk / 3;
    const int sg = blk - tile * 3;
    const int t = threadIdx.x;
    const int l = t & 63, w = t >> 6;
    const int r0 = tile * 64;
    const int rbase = w * 16 + (l >> 4) * 4;
    const int cbase = (l & 15) * 4;
    float acc[4][4] = {};

    #pragma unroll
    for (int ch = 0; ch < 4; ++ch) {
        const int koff = ch * 32;
        #pragma unroll
        for (int i = 0; i < 2; ++i) {
            int f   = i * 256 + t;
            int row = f >> 3;
            int kq  = f & 7;
            int gr  = r0 + row; if (gr > N_NODES - 1) gr = N_NODES - 1;
            float4 v = *(const float4*)(X + (size_t)gr * IN_DIM + koff + kq * 4);
            At[(kq * 4 + 0) * AT_STRIDE + row] = v.x;
            At[(kq * 4 + 1) * AT_STRIDE + row] = v.y;
            At[(kq * 4 + 2) * AT_STRIDE + row] = v.z;
            At[(kq * 4 + 3) * AT_STRIDE + row] = v.w;
        }
        {
            const float4* Wg = (const float4*)(W1 + ((size_t)sg * 128 + koff) * 64);
            float4 wtmp[2];
            #pragma unroll
            for (int i = 0; i < 2; ++i) wtmp[i] = Wg[i * 256 + t];
            __syncthreads();
            #pragma unroll
            for (int i = 0; i < 2; ++i) *(float4*)&Wl[(i * 256 + t) * 4] = wtmp[i];
            __syncthreads();
        }
        #pragma unroll 8
        for (int k = 0; k < 32; ++k) {
            float4 a4 = *(const float4*)&At[k * AT_STRIDE + rbase];
            float4 w4 = *(const float4*)&Wl[k * 64 + cbase];
            acc[0][0] += a4.x * w4.x; acc[0][1] += a4.x * w4.y; acc[0][2] += a4.x * w4.z; acc[0][3] += a4.x * w4.w;
            acc[1][0] += a4.y * w4.x; acc[1][1] += a4.y * w4.y; acc[1][2] += a4.y * w4.z; acc[1][3] += a4.y * w4.w;
            acc[2][0] += a4.z * w4.x; acc[2][1] += a4.z * w4.y; acc[2][2] += a4.z * w4.z; acc[2][3] += a4.z * w4.w;
            acc[3][0] += a4.w * w4.x; acc[3][1] += a4.w * w4.y; acc[3][2] += a4.w * w4.z; acc[3][3] += a4.w * w4.w;
        }
        __syncthreads();
    }
    uint2* Gout = (sg == 0) ? G0bf : (sg == 1) ? G1bf : G2bf;
    #pragma unroll
    for (int r = 0; r < 4; ++r) {
        int gr = r0 + rbase + r;
        if (gr < N_NODES) {
            float4 o = {acc[r][0], acc[r][1], acc[r][2], acc[r][3]};
            Gout[(size_t)gr * 16 + (l & 15)] = pack_f4(o);
        }
    }
}

// ---------------- bf16-gather SpMM: wave = 4 nodes, 16 lanes/row ----------------
// MODE 0: Rbf = A(G1bf) + 2*acc(src=G2bf)
// MODE 1: hbf = dis*(acc(src=Rbf) + A(G0bf) - B(G2bf))
template<int MODE>
__global__ __launch_bounds__(256) void k_spmm64v(const int* __restrict__ cnt0,
                          const unsigned int* __restrict__ pack,
                          const uint2* __restrict__ srcbf, const uint2* __restrict__ Abf,
                          const uint2* __restrict__ Bbf, const int* __restrict__ cnt1,
                          uint2* __restrict__ dstbf) {
    int t = blockIdx.x * blockDim.x + threadIdx.x;
    int wid = t >> 6, lane = t & 63;
    int grp = lane >> 4, sub = lane & 15;
    int node = wid * 4 + grp;
    if (node >= N_NODES) return;
    int s = node * CAP;
    int e = s + cnt0[node];
    float4 acc = {0.f, 0.f, 0.f, 0.f};
    int j = s;
    for (; j + 3 < e; j += 4) {
        unsigned int p0 = pack[j], p1 = pack[j + 1], p2 = pack[j + 2], p3 = pack[j + 3];
        float4 r0 = unpack_f4(srcbf[(size_t)(p0 >> 16) * 16 + sub]);
        float4 r1 = unpack_f4(srcbf[(size_t)(p1 >> 16) * 16 + sub]);
        float4 r2 = unpack_f4(srcbf[(size_t)(p2 >> 16) * 16 + sub]);
        float4 r3 = unpack_f4(srcbf[(size_t)(p3 >> 16) * 16 + sub]);
        float v0 = __half2float(__ushort_as_half((unsigned short)(p0 & 0xffffu)));
        float v1 = __half2float(__ushort_as_half((unsigned short)(p1 & 0xffffu)));
        float v2 = __half2float(__ushort_as_half((unsigned short)(p2 & 0xffffu)));
        float v3 = __half2float(__ushort_as_half((unsigned short)(p3 & 0xffffu)));
        acc.x += v0 * r0.x + v1 * r1.x + v2 * r2.x + v3 * r3.x;
        acc.y += v0 * r0.y + v1 * r1.y + v2 * r2.y + v3 * r3.y;
        acc.z += v0 * r0.z + v1 * r1.z + v2 * r2.z + v3 * r3.z;
        acc.w += v0 * r0.w + v1 * r1.w + v2 * r2.w + v3 * r3.w;
    }
    for (; j < e; ++j) {
        unsigned int p = pack[j];
        float4 r = unpack_f4(srcbf[(size_t)(p >> 16) * 16 + sub]);
        float v = __half2float(__ushort_as_half((unsigned short)(p & 0xffffu)));
        acc.x += v * r.x; acc.y += v * r.y; acc.z += v * r.z; acc.w += v * r.w;
    }
    size_t idx = (size_t)node * 16 + sub;
    float4 a = unpack_f4(Abf[idx]);
    float4 o;
    if (MODE == 0) {
        o.x = a.x + 2.f * acc.x; o.y = a.y + 2.f * acc.y;
        o.z = a.z + 2.f * acc.z; o.w = a.w + 2.f * acc.w;
    } else {
        float4 bb = unpack_f4(Bbf[idx]);
        float d = rsqrtf(1.0f + (float)cnt1[node]);
        o.x = d * (acc.x + a.x - bb.x); o.y = d * (acc.y + a.y - bb.y);
        o.z = d * (acc.z + a.z - bb.z); o.w = d * (acc.w + a.w - bb.w);
    }
    dstbf[idx] = pack_f4(o);
}

// ---------------- fused conv + 64x64 GEMM: block = 16 nodes ----------------
__global__ __launch_bounds__(256) void k_conv_gemm(const int* __restrict__ cnt1,
                                                   const int* __restrict__ csrc,
                                                   const uint2* __restrict__ hin,
                                                   const float* __restrict__ b,
                                                   const float* __restrict__ W,
                                                   uint2* __restrict__ xout,
                                                   uint2* __restrict__ hout) {
    __shared__ float xl[16][64];
    __shared__ float4 Wl4[64 * 16];
    int t = threadIdx.x;
    int gt = blockIdx.x * 256 + t;
    int wid = gt >> 6, lane = t & 63;
    int grp = lane >> 4, sub = lane & 15;
    int node = wid * 4 + grp;
    int ln = ((t >> 6) << 2) + grp;
    int deg = cnt1[node];
    int s = node * CAP;
    int e = s + deg;
    float4 acc = {0.f, 0.f, 0.f, 0.f};
    int j = s;
    for (; j + 3 < e; j += 4) {
        int s0 = csrc[j], s1 = csrc[j + 1], s2 = csrc[j + 2], s3 = csrc[j + 3];
        float4 r0 = unpack_f4(hin[(size_t)s0 * 16 + sub]);
        float4 r1 = unpack_f4(hin[(size_t)s1 * 16 + sub]);
        float4 r2 = unpack_f4(hin[(size_t)s2 * 16 + sub]);
        float4 r3 = unpack_f4(hin[(size_t)s3 * 16 + sub]);
        acc.x += (r0.x + r1.x) + (r2.x + r3.x);
        acc.y += (r0.y + r1.y) + (r2.y + r3.y);
        acc.z += (r0.z + r1.z) + (r2.z + r3.z);
        acc.w += (r0.w + r1.w) + (r2.w + r3.w);
    }
    for (; j < e; ++j) {
        float4 r = unpack_f4(hin[(size_t)csrc[j] * 16 + sub]);
        acc.x += r.x; acc.y += r.y; acc.z += r.z; acc.w += r.w;
    }
    size_t idx = (size_t)node * 16 + sub;
    float4 sl = unpack_f4(hin[idx]);
    float d = rsqrtf(1.0f + (float)deg);
    float4 bv = ((const float4*)b)[sub];
    float4 o;
    o.x = fmaxf(d * (acc.x + sl.x) + bv.x, 0.f);
    o.y = fmaxf(d * (acc.y + sl.y) + bv.y, 0.f);
    o.z = fmaxf(d * (acc.z + sl.z) + bv.z, 0.f);
    o.w = fmaxf(d * (acc.w + sl.w) + bv.w, 0.f);
    xout[idx] = pack_f4(o);
    xl[ln][sub * 4 + 0] = o.x;
    xl[ln][sub * 4 + 1] = o.y;
    xl[ln][sub * 4 + 2] = o.z;
    xl[ln][sub * 4 + 3] = o.w;
    {
        const float4* Wg = (const float4*)W;
        #pragma unroll
        for (int i = 0; i < 4; ++i) Wl4[i * 256 + t] = Wg[i * 256 + t];
    }
    __syncthreads();
    int n = t >> 4, c4 = t & 15;
    float4 h4 = {0.f, 0.f, 0.f, 0.f};
    #pragma unroll 8
    for (int k = 0; k < 64; ++k) {
        float xv = xl[n][k];
        float4 w4 = Wl4[k * 16 + c4];
        h4.x += xv * w4.x; h4.y += xv * w4.y; h4.z += xv * w4.z; h4.w += xv * w4.w;
    }
    int gnode = blockIdx.x * 16 + n;
    float dn = rsqrtf(1.0f + (float)cnt1[gnode]);
    h4.x *= dn; h4.y *= dn; h4.z *= dn; h4.w *= dn;
    hout[(size_t)gnode * 16 + c4] = pack_f4(h4);
}

// ---------------- final conv: xm = (x1 + x2 + relu(...))/3  (fp32, feeds pool) ----------------
__global__ void k_conv_final(const int* __restrict__ cnt1, const int* __restrict__ csrc,
                             const uint2* __restrict__ hin,
                             const float* __restrict__ b,
                             const uint2* __restrict__ x1bf, const uint2* __restrict__ x2bf,
                             float4* __restrict__ outf) {
    int t = blockIdx.x * blockDim.x + threadIdx.x;
    int wid = t >> 6, lane = t & 63;
    int grp = lane >> 4, sub = lane & 15;
    int node = wid * 4 + grp;
    if (node >= N_NODES) return;
    int deg = cnt1[node];
    int s = node * CAP;
    int e = s + deg;
    float4 acc = {0.f, 0.f, 0.f, 0.f};
    int j = s;
    for (; j + 3 < e; j += 4) {
        int s0 = csrc[j], s1 = csrc[j + 1], s2 = csrc[j + 2], s3 = csrc[j + 3];
        float4 r0 = unpack_f4(hin[(size_t)s0 * 16 + sub]);
        float4 r1 = unpack_f4(hin[(size_t)s1 * 16 + sub]);
        float4 r2 = unpack_f4(hin[(size_t)s2 * 16 + sub]);
        float4 r3 = unpack_f4(hin[(size_t)s3 * 16 + sub]);
        acc.x += (r0.x + r1.x) + (r2.x + r3.x);
        acc.y += (r0.y + r1.y) + (r2.y + r3.y);
        acc.z += (r0.z + r1.z) + (r2.z + r3.z);
        acc.w += (r0.w + r1.w) + (r2.w + r3.w);
    }
    for (; j < e; ++j) {
        float4 r = unpack_f4(hin[(size_t)csrc[j] * 16 + sub]);
        acc.x += r.x; acc.y += r.y; acc.z += r.z; acc.w += r.w;
    }
    size_t idx = (size_t)node * 16 + sub;
    float4 sl = unpack_f4(hin[idx]);
    float d = rsqrtf(1.0f + (float)deg);
    float4 bv = ((const float4*)b)[sub];
    float4 o;
    o.x = fmaxf(d * (acc.x + sl.x) + bv.x, 0.f);
    o.y = fmaxf(d * (acc.y + sl.y) + bv.y, 0.f);
    o.z = fmaxf(d * (acc.z + sl.z) + bv.z, 0.f);
    o.w = fmaxf(d * (acc.w + sl.w) + bv.w, 0.f);
    float4 a1 = unpack_f4(x1bf[idx]), a2 = unpack_f4(x2bf[idx]);
    const float third = 1.f / 3.f;
    o.x = (a1.x + a2.x + o.x) * third;
    o.y = (a1.y + a2.y + o.y) * third;
    o.z = (a1.z + a2.z + o.z) * third;
    o.w = (a1.w + a2.w + o.w) * third;
    outf[idx] = o;
}

// ---------------- pool (batch sorted -> contiguous ranges) + head, 4 waves ----------------
__global__ __launch_bounds__(256) void k_pool_out(const float* __restrict__ xm,
                           const int* __restrict__ batch,
                           const float* __restrict__ Wout, const float* __restrict__ bout,
                           float* __restrict__ out) {
    __shared__ float red[4][64];
    __shared__ float sh[64];
    __shared__ float logits[OUT_DIM];
    int g = blockIdx.x;
    int t = threadIdx.x, f = t & 63, w = t >> 6;
    int lo = 0, hi = N_NODES;
    while (lo < hi) { int m = (lo + hi) >> 1; if (batch[m] < g) lo = m + 1; else hi = m; }
    int start = lo;
    hi = N_NODES;
    while (lo < hi) { int m = (lo + hi) >> 1; if (batch[m] < g + 1) lo = m + 1; else hi = m; }
    int end = lo;
    float a = 0.f;
    for (int i = start + w; i < end; i += 4)
        a += xm[(size_t)i * 64 + f];
    red[w][f] = a;
    __syncthreads();
    if (w == 0) {
        float cnt = (float)((end - start) > 0 ? (end - start) : 1);
        sh[f] = (red[0][f] + red[1][f] + red[2][f] + red[3][f]) / cnt;
    }
    __syncthreads();
    if (t < OUT_DIM) {
        float l = bout[t];
        for (int k = 0; k < 64; ++k) l += sh[k] * Wout[k * OUT_DIM + t];
        logits[t] = l;
    }
    __syncthreads();
    if (t < OUT_DIM) {
        float m = logits[0];
        for (int k = 1; k < OUT_DIM; ++k) m = fmaxf(m, logits[k]);
        float ssum = 0.f;
        for (int k = 0; k < OUT_DIM; ++k) ssum += expf(logits[k] - m);
        out[(size_t)g * OUT_DIM + t] = expf(logits[t] - m) / ssum;
    }
}

extern "C" void kernel_launch(void* const* d_in, const int* in_sizes, int n_in,
                              void* d_out, int out_size, void* d_ws, size_t ws_size,
                              hipStream_t stream) {
    const float* X     = (const float*)d_in[0];
    const int*   Lind  = (const int*)d_in[1];
    const int*   ind0  = Lind;
    const int*   ind1  = Lind + N_EDGES;
    const float* vals  = (const float*)d_in[2];
    const int*   batch = (const int*)d_in[3];
    const float* W1    = (const float*)d_in[4];
    const float* b1    = (const float*)d_in[5];
    const float* W2    = (const float*)d_in[6];
    const float* b2    = (const float*)d_in[7];
    const float* W3    = (const float*)d_in[8];
    const float* b3    = (const float*)d_in[9];
    const float* Wout  = (const float*)d_in[10];
    const float* bout  = (const float*)d_in[11];
    float* out = (float*)d_out;

    // workspace layout (4B words)
    int* cnt0    = (int*)d_ws;                        // 50000 (written by binB, no zeroing)
    int* cnt1    = cnt0 + 50000;                      // 50000
    int* gcur    = cnt1 + 50000;                      // 400 (2*NRANGE used) -> 100400 (even)
    uint2* c0seg = (uint2*)(gcur + 400);              // NRANGE*SEGCAP uint2 = 1,806,336 words
    unsigned int* c1seg = (unsigned int*)(c0seg + (size_t)NRANGE * SEGCAP);  // 903,168 words
    unsigned int* c0pack = c1seg + (size_t)NRANGE * SEGCAP;   // 2,400,000
    int*  c1src  = (int*)(c0pack + 50000 * CAP);      // 2,400,000
    uint2* G0bf  = (uint2*)(c1src + 50000 * CAP);     // word 7,609,904 (even -> 8B aligned)
    uint2* G1bf  = G0bf + 800000;
    uint2* G2bf  = G1bf + 800000;
    uint2* Rbf   = G2bf + 800000;
    uint2* hbf   = Rbf + 800000;
    uint2* h2bf  = hbf + 800000;
    float* xm    = (float*)(h2bf + 800000);           // word 17,209,904 (%4==0 -> 16B aligned)
    // bf16 buffer reuse after producers die:
    uint2* x1bf  = G0bf;   // G0 dead after spmm1
    uint2* x2bf  = G1bf;   // G1 dead after spmm0

    const int B = 256;
    const int gatherGrid = 12500 * 64 / B;                // 3125 blocks (4 nodes/wave)

    // two-phase CSR build: bin by node-range, then LDS counting build (no global bucket atomics)
    k_zero_int<<<2, B, 0, stream>>>(gcur, 2 * NRANGE);
    k_binA<<<NCHUNKS, B, 0, stream>>>(ind0, ind1, vals, gcur, c0seg, c1seg);
    k_binB<<<2 * NRANGE, B, 0, stream>>>(gcur, c0seg, c1seg, c0pack, c1src, cnt0, cnt1);

    // layer-1 GEMMs: one segment per block (3x grid, BK=32)
    k_gemm1seg<<<GEMM_BLOCKS * 3, B, 0, stream>>>(X, W1, G0bf, G1bf, G2bf);

    // Chebyshev via linearity (64-dim spmms, bf16 gathers):
    // R = G1 + 2*(L@G2);  h1' = dis*(L@R + G0 - G2)
    k_spmm64v<0><<<gatherGrid, B, 0, stream>>>(cnt0, c0pack, G2bf, G1bf, nullptr, cnt1, Rbf);
    k_spmm64v<1><<<gatherGrid, B, 0, stream>>>(cnt0, c0pack, Rbf, G0bf, G2bf, cnt1, hbf);

    // layer 1 conv + layer-2 GEMM fused: reads hbf, writes x1bf + h2bf
    k_conv_gemm<<<gatherGrid, B, 0, stream>>>(cnt1, c1src, hbf, b1, W2, x1bf, h2bf);

    // layer 2 conv + layer-3 GEMM fused: reads h2bf, writes x2bf + hbf
    k_conv_gemm<<<gatherGrid, B, 0, stream>>>(cnt1, c1src, h2bf, b2, W3, x2bf, hbf);

    // layer 3 conv (final): reads hbf, writes xm = (x1+x2+x3)/3
    k_conv_final<<<gatherGrid, B, 0, stream>>>(cnt1, c1src, hbf, b3, x1bf, x2bf, (float4*)xm);

    // pool + head
    k_pool_out<<<N_GRAPHS, B, 0, stream>>>(xm, batch, Wout, bout, out);
}

// Round 24
// 217.413 us; speedup vs baseline: 1.5086x; 1.1105x over previous
//
#include <hip/hip_runtime.h>
#include <hip/hip_bf16.h>
#include <hip/hip_fp16.h>

#define N_NODES 50000
#define N_EDGES 800000
#define IN_DIM 128
#define F_SIZE 64
#define N_GRAPHS 512
#define OUT_DIM 10
#define EDGE_CHUNK 2048
#define NCHUNKS ((N_EDGES + EDGE_CHUNK - 1) / EDGE_CHUNK)   // 391
#define GEMM_BLOCKS 782        // ceil(50000/64)
#define CAP 48                 // per-node CSR bucket capacity (max degree ~45 @ Poisson(16))
#define NRANGE 196             // node ranges of 256 (50000 >> 8 -> 0..195)
#define SEGCAP 4608            // entries per range segment (mean 4096, +8 sigma)

typedef __attribute__((ext_vector_type(8))) short short8;
typedef __attribute__((ext_vector_type(4))) float f32x4;

// ---------------- bf16 pack/unpack helpers (round-to-nearest-even) ----------------
__device__ __forceinline__ unsigned int pack_bf2(float a, float b) {
    unsigned int ua = __float_as_uint(a);
    unsigned int ub = __float_as_uint(b);
    ua += 0x7fffu + ((ua >> 16) & 1u);
    ub += 0x7fffu + ((ub >> 16) & 1u);
    return (ua >> 16) | (ub & 0xffff0000u);
}
__device__ __forceinline__ uint2 pack_f4(float4 o) {
    return make_uint2(pack_bf2(o.x, o.y), pack_bf2(o.z, o.w));
}
__device__ __forceinline__ float4 unpack_f4(uint2 u) {
    float4 f;
    f.x = __uint_as_float(u.x << 16);
    f.y = __uint_as_float(u.x & 0xffff0000u);
    f.z = __uint_as_float(u.y << 16);
    f.w = __uint_as_float(u.y & 0xffff0000u);
    return f;
}
__device__ __forceinline__ unsigned short bf1(float x) {
    unsigned int u = __float_as_uint(x);
    u += 0x7fffu + ((u >> 16) & 1u);
    return (unsigned short)(u >> 16);
}

// ---------------- utility ----------------
__global__ void k_zero_int(int* __restrict__ p, int n) {
    int i = blockIdx.x * blockDim.x + threadIdx.x;
    if (i < n) p[i] = 0;
}

// ---------------- prep: W1 -> MFMA B-frag swizzle (blocks 0..47), X -> bf16 (rest) ----------------
// B-frag for (sg, ktile, ctile): lane l, elem j = W1[(sg*128 + ktile*32 + (l>>4)*8 + j)][ctile*16 + (l&15)]
__global__ __launch_bounds__(256) void k_prep(const float* __restrict__ X,
                                              const float* __restrict__ W1,
                                              unsigned short* __restrict__ Xbf,
                                              unsigned short* __restrict__ Wsw) {
    int t = threadIdx.x;
    if (blockIdx.x < 48) {
        if (t < 64) {
            int frag = blockIdx.x;          // ((sg*4 + kt)*4 + ct)
            int ct = frag & 3;
            int kt = (frag >> 2) & 3;
            int sg = frag >> 4;
            #pragma unroll
            for (int j = 0; j < 8; ++j) {
                int k = sg * 128 + kt * 32 + (t >> 4) * 8 + j;
                int col = ct * 16 + (t & 15);
                Wsw[frag * 512 + t * 8 + j] = bf1(W1[k * 64 + col]);
            }
        }
        return;
    }
    long idx = (long)(blockIdx.x - 48) * 256 + t;   // float4 id
    if (idx < (long)N_NODES * IN_DIM / 4) {
        float4 v = ((const float4*)X)[idx];
        ((uint2*)Xbf)[idx] = pack_f4(v);
    }
}

// ---------------- Phase A: bin edges by node-range (one edge read, LDS hist) ----------------
__global__ __launch_bounds__(256) void k_binA(const int* __restrict__ ind0,
                                              const int* __restrict__ ind1,
                                              const float* __restrict__ vals,
                                              int* __restrict__ gcur,
                                              uint2* __restrict__ c0seg,
                                              unsigned int* __restrict__ c1seg) {
    __shared__ int h0[NRANGE], h1[NRANGE], b0[NRANGE], b1[NRANGE];
    int t = threadIdx.x;
    if (t < NRANGE) { h0[t] = 0; h1[t] = 0; }
    __syncthreads();
    int base = blockIdx.x * EDGE_CHUNK;
    int r[8], c[8]; unsigned int hv[8];
    #pragma unroll
    for (int i = 0; i < 8; ++i) {
        int e = base + i * 256 + t;
        if (e < N_EDGES) {
            r[i] = ind0[e]; c[i] = ind1[e];
            hv[i] = (unsigned int)__half_as_ushort(__float2half(vals[e]));
            atomicAdd(&h0[r[i] >> 8], 1);
            atomicAdd(&h1[c[i] >> 8], 1);
        } else r[i] = -1;
    }
    __syncthreads();
    if (t < NRANGE) {
        b0[t] = atomicAdd(&gcur[t], h0[t]);
        b1[t] = atomicAdd(&gcur[NRANGE + t], h1[t]);
        h0[t] = 0; h1[t] = 0;
    }
    __syncthreads();
    #pragma unroll
    for (int i = 0; i < 8; ++i) {
        if (r[i] >= 0) {
            int bin0 = r[i] >> 8;
            int off0 = b0[bin0] + atomicAdd(&h0[bin0], 1);
            c0seg[(size_t)bin0 * SEGCAP + off0] =
                make_uint2(((unsigned int)(r[i] & 255) << 16) | hv[i], (unsigned int)c[i]);
            int bin1 = c[i] >> 8;
            int off1 = b1[bin1] + atomicAdd(&h1[bin1], 1);
            c1seg[(size_t)bin1 * SEGCAP + off1] =
                ((unsigned int)(c[i] & 255) << 16) | (unsigned int)r[i];
        }
    }
}

// ---------------- Phase B: per-range counting build (LDS cursors, no global atomics) ----------------
__global__ __launch_bounds__(256) void k_binB(const int* __restrict__ gcur,
                                              const uint2* __restrict__ c0seg,
                                              const unsigned int* __restrict__ c1seg,
                                              unsigned int* __restrict__ c0pack,
                                              int* __restrict__ c1src,
                                              int* __restrict__ cnt0,
                                              int* __restrict__ cnt1) {
    __shared__ int cur[256];
    int t = threadIdx.x;
    int range = blockIdx.x >> 1;
    int side = blockIdx.x & 1;
    cur[t] = 0;
    __syncthreads();
    int nodeBase = range << 8;
    if (side == 0) {
        int n = gcur[range];
        for (int i = t; i < n; i += 256) {
            uint2 en = c0seg[(size_t)range * SEGCAP + i];
            int rlow = en.x >> 16;
            int node = nodeBase + rlow;
            int k = atomicAdd(&cur[rlow], 1);
            c0pack[(size_t)node * CAP + k] = (en.y << 16) | (en.x & 0xffffu);
        }
        __syncthreads();
        int node = nodeBase + t;
        if (node < N_NODES) cnt0[node] = cur[t];
    } else {
        int n = gcur[NRANGE + range];
        for (int i = t; i < n; i += 256) {
            unsigned int en = c1seg[(size_t)range * SEGCAP + i];
            int clow = (en >> 16) & 0xff;
            int node = nodeBase + clow;
            int k = atomicAdd(&cur[clow], 1);
            c1src[(size_t)node * CAP + k] = (int)(en & 0xffffu);
        }
        __syncthreads();
        int node = nodeBase + t;
        if (node < N_NODES) cnt1[node] = cur[t];
    }
}

// ---------------- layer-1 GEMM via bf16 MFMA: block = 64x64 tile, one segment ----------------
// No LDS, no barriers. A frag: lane l holds X[row = r0 + (l&15)][k = koff + (l>>4)*8 + j].
// C/D: col = lane&15, row = (lane>>4)*4 + reg (verified mapping).
__global__ __launch_bounds__(256) void k_gemm1mfma(const unsigned short* __restrict__ Xbf,
                                                   const unsigned short* __restrict__ Wsw,
                                                   uint2* __restrict__ G0bf,
                                                   uint2* __restrict__ G1bf,
                                                   uint2* __restrict__ G2bf) {
    int blk = blockIdx.x;
    int tile = blk / 3, sg = blk - tile * 3;
    int t = threadIdx.x;
    int w = t >> 6, l = t & 63;
    int r0 = tile * 64 + w * 16;
    int arow = r0 + (l & 15); if (arow > N_NODES - 1) arow = N_NODES - 1;
    const unsigned short* ap = Xbf + (size_t)arow * IN_DIM + (l >> 4) * 8;
    short8 a[4];
    #pragma unroll
    for (int kt = 0; kt < 4; ++kt)
        a[kt] = *(const short8*)(ap + kt * 32);
    unsigned short* Gout_us = (unsigned short*)((sg == 0) ? G0bf : (sg == 1) ? G1bf : G2bf);
    #pragma unroll
    for (int ct = 0; ct < 4; ++ct) {
        f32x4 acc = {0.f, 0.f, 0.f, 0.f};
        #pragma unroll
        for (int kt = 0; kt < 4; ++kt) {
            short8 b = *(const short8*)(Wsw + ((size_t)((sg * 4 + kt) * 4 + ct)) * 512 + l * 8);
            acc = __builtin_amdgcn_mfma_f32_16x16x32_bf16(a[kt], b, acc, 0, 0, 0);
        }
        int col = ct * 16 + (l & 15);
        #pragma unroll
        for (int i = 0; i < 4; ++i) {
            int grow = r0 + (l >> 4) * 4 + i;
            if (grow < N_NODES)
                Gout_us[(size_t)grow * 64 + col] = bf1(acc[i]);
        }
    }
}

// ---------------- bf16-gather SpMM: wave = 4 nodes, 16 lanes/row ----------------
// MODE 0: Rbf = A(G1bf) + 2*acc(src=G2bf)
// MODE 1: hbf = dis*(acc(src=Rbf) + A(G0bf) - B(G2bf))
template<int MODE>
__global__ __launch_bounds__(256) void k_spmm64v(const int* __restrict__ cnt0,
                          const unsigned int* __restrict__ pack,
                          const uint2* __restrict__ srcbf, const uint2* __restrict__ Abf,
                          const uint2* __restrict__ Bbf, const int* __restrict__ cnt1,
                          uint2* __restrict__ dstbf) {
    int t = blockIdx.x * blockDim.x + threadIdx.x;
    int wid = t >> 6, lane = t & 63;
    int grp = lane >> 4, sub = lane & 15;
    int node = wid * 4 + grp;
    if (node >= N_NODES) return;
    int s = node * CAP;
    int e = s + cnt0[node];
    float4 acc = {0.f, 0.f, 0.f, 0.f};
    int j = s;
    for (; j + 3 < e; j += 4) {
        unsigned int p0 = pack[j], p1 = pack[j + 1], p2 = pack[j + 2], p3 = pack[j + 3];
        float4 r0 = unpack_f4(srcbf[(size_t)(p0 >> 16) * 16 + sub]);
        float4 r1 = unpack_f4(srcbf[(size_t)(p1 >> 16) * 16 + sub]);
        float4 r2 = unpack_f4(srcbf[(size_t)(p2 >> 16) * 16 + sub]);
        float4 r3 = unpack_f4(srcbf[(size_t)(p3 >> 16) * 16 + sub]);
        float v0 = __half2float(__ushort_as_half((unsigned short)(p0 & 0xffffu)));
        float v1 = __half2float(__ushort_as_half((unsigned short)(p1 & 0xffffu)));
        float v2 = __half2float(__ushort_as_half((unsigned short)(p2 & 0xffffu)));
        float v3 = __half2float(__ushort_as_half((unsigned short)(p3 & 0xffffu)));
        acc.x += v0 * r0.x + v1 * r1.x + v2 * r2.x + v3 * r3.x;
        acc.y += v0 * r0.y + v1 * r1.y + v2 * r2.y + v3 * r3.y;
        acc.z += v0 * r0.z + v1 * r1.z + v2 * r2.z + v3 * r3.z;
        acc.w += v0 * r0.w + v1 * r1.w + v2 * r2.w + v3 * r3.w;
    }
    for (; j < e; ++j) {
        unsigned int p = pack[j];
        float4 r = unpack_f4(srcbf[(size_t)(p >> 16) * 16 + sub]);
        float v = __half2float(__ushort_as_half((unsigned short)(p & 0xffffu)));
        acc.x += v * r.x; acc.y += v * r.y; acc.z += v * r.z; acc.w += v * r.w;
    }
    size_t idx = (size_t)node * 16 + sub;
    float4 a = unpack_f4(Abf[idx]);
    float4 o;
    if (MODE == 0) {
        o.x = a.x + 2.f * acc.x; o.y = a.y + 2.f * acc.y;
        o.z = a.z + 2.f * acc.z; o.w = a.w + 2.f * acc.w;
    } else {
        float4 bb = unpack_f4(Bbf[idx]);
        float d = rsqrtf(1.0f + (float)cnt1[node]);
        o.x = d * (acc.x + a.x - bb.x); o.y = d * (acc.y + a.y - bb.y);
        o.z = d * (acc.z + a.z - bb.z); o.w = d * (acc.w + a.w - bb.w);
    }
    dstbf[idx] = pack_f4(o);
}

// ---------------- fused conv + 64x64 GEMM: block = 16 nodes ----------------
__global__ __launch_bounds__(256) void k_conv_gemm(const int* __restrict__ cnt1,
                                                   const int* __restrict__ csrc,
                                                   const uint2* __restrict__ hin,
                                                   const float* __restrict__ b,
                                                   const float* __restrict__ W,
                                                   uint2* __restrict__ xout,
                                                   uint2* __restrict__ hout) {
    __shared__ float xl[16][64];
    __shared__ float4 Wl4[64 * 16];
    int t = threadIdx.x;
    int gt = blockIdx.x * 256 + t;
    int wid = gt >> 6, lane = t & 63;
    int grp = lane >> 4, sub = lane & 15;
    int node = wid * 4 + grp;
    int ln = ((t >> 6) << 2) + grp;
    int deg = cnt1[node];
    int s = node * CAP;
    int e = s + deg;
    float4 acc = {0.f, 0.f, 0.f, 0.f};
    int j = s;
    for (; j + 3 < e; j += 4) {
        int s0 = csrc[j], s1 = csrc[j + 1], s2 = csrc[j + 2], s3 = csrc[j + 3];
        float4 r0 = unpack_f4(hin[(size_t)s0 * 16 + sub]);
        float4 r1 = unpack_f4(hin[(size_t)s1 * 16 + sub]);
        float4 r2 = unpack_f4(hin[(size_t)s2 * 16 + sub]);
        float4 r3 = unpack_f4(hin[(size_t)s3 * 16 + sub]);
        acc.x += (r0.x + r1.x) + (r2.x + r3.x);
        acc.y += (r0.y + r1.y) + (r2.y + r3.y);
        acc.z += (r0.z + r1.z) + (r2.z + r3.z);
        acc.w += (r0.w + r1.w) + (r2.w + r3.w);
    }
    for (; j < e; ++j) {
        float4 r = unpack_f4(hin[(size_t)csrc[j] * 16 + sub]);
        acc.x += r.x; acc.y += r.y; acc.z += r.z; acc.w += r.w;
    }
    size_t idx = (size_t)node * 16 + sub;
    float4 sl = unpack_f4(hin[idx]);
    float d = rsqrtf(1.0f + (float)deg);
    float4 bv = ((const float4*)b)[sub];
    float4 o;
    o.x = fmaxf(d * (acc.x + sl.x) + bv.x, 0.f);
    o.y = fmaxf(d * (acc.y + sl.y) + bv.y, 0.f);
    o.z = fmaxf(d * (acc.z + sl.z) + bv.z, 0.f);
    o.w = fmaxf(d * (acc.w + sl.w) + bv.w, 0.f);
    xout[idx] = pack_f4(o);
    xl[ln][sub * 4 + 0] = o.x;
    xl[ln][sub * 4 + 1] = o.y;
    xl[ln][sub * 4 + 2] = o.z;
    xl[ln][sub * 4 + 3] = o.w;
    {
        const float4* Wg = (const float4*)W;
        #pragma unroll
        for (int i = 0; i < 4; ++i) Wl4[i * 256 + t] = Wg[i * 256 + t];
    }
    __syncthreads();
    int n = t >> 4, c4 = t & 15;
    float4 h4 = {0.f, 0.f, 0.f, 0.f};
    #pragma unroll 8
    for (int k = 0; k < 64; ++k) {
        float xv = xl[n][k];
        float4 w4 = Wl4[k * 16 + c4];
        h4.x += xv * w4.x; h4.y += xv * w4.y; h4.z += xv * w4.z; h4.w += xv * w4.w;
    }
    int gnode = blockIdx.x * 16 + n;
    float dn = rsqrtf(1.0f + (float)cnt1[gnode]);
    h4.x *= dn; h4.y *= dn; h4.z *= dn; h4.w *= dn;
    hout[(size_t)gnode * 16 + c4] = pack_f4(h4);
}

// ---------------- final conv: xm = (x1 + x2 + relu(...))/3  (fp32, feeds pool) ----------------
__global__ void k_conv_final(const int* __restrict__ cnt1, const int* __restrict__ csrc,
                             const uint2* __restrict__ hin,
                             const float* __restrict__ b,
                             const uint2* __restrict__ x1bf, const uint2* __restrict__ x2bf,
                             float4* __restrict__ outf) {
    int t = blockIdx.x * blockDim.x + threadIdx.x;
    int wid = t >> 6, lane = t & 63;
    int grp = lane >> 4, sub = lane & 15;
    int node = wid * 4 + grp;
    if (node >= N_NODES) return;
    int deg = cnt1[node];
    int s = node * CAP;
    int e = s + deg;
    float4 acc = {0.f, 0.f, 0.f, 0.f};
    int j = s;
    for (; j + 3 < e; j += 4) {
        int s0 = csrc[j], s1 = csrc[j + 1], s2 = csrc[j + 2], s3 = csrc[j + 3];
        float4 r0 = unpack_f4(hin[(size_t)s0 * 16 + sub]);
        float4 r1 = unpack_f4(hin[(size_t)s1 * 16 + sub]);
        float4 r2 = unpack_f4(hin[(size_t)s2 * 16 + sub]);
        float4 r3 = unpack_f4(hin[(size_t)s3 * 16 + sub]);
        acc.x += (r0.x + r1.x) + (r2.x + r3.x);
        acc.y += (r0.y + r1.y) + (r2.y + r3.y);
        acc.z += (r0.z + r1.z) + (r2.z + r3.z);
        acc.w += (r0.w + r1.w) + (r2.w + r3.w);
    }
    for (; j < e; ++j) {
        float4 r = unpack_f4(hin[(size_t)csrc[j] * 16 + sub]);
        acc.x += r.x; acc.y += r.y; acc.z += r.z; acc.w += r.w;
    }
    size_t idx = (size_t)node * 16 + sub;
    float4 sl = unpack_f4(hin[idx]);
    float d = rsqrtf(1.0f + (float)deg);
    float4 bv = ((const float4*)b)[sub];
    float4 o;
    o.x = fmaxf(d * (acc.x + sl.x) + bv.x, 0.f);
    o.y = fmaxf(d * (acc.y + sl.y) + bv.y, 0.f);
    o.z = fmaxf(d * (acc.z + sl.z) + bv.z, 0.f);
    o.w = fmaxf(d * (acc.w + sl.w) + bv.w, 0.f);
    float4 a1 = unpack_f4(x1bf[idx]), a2 = unpack_f4(x2bf[idx]);
    const float third = 1.f / 3.f;
    o.x = (a1.x + a2.x + o.x) * third;
    o.y = (a1.y + a2.y + o.y) * third;
    o.z = (a1.z + a2.z + o.z) * third;
    o.w = (a1.w + a2.w + o.w) * third;
    outf[idx] = o;
}

// ---------------- pool (batch sorted -> contiguous ranges) + head, 4 waves ----------------
__global__ __launch_bounds__(256) void k_pool_out(const float* __restrict__ xm,
                           const int* __restrict__ batch,
                           const float* __restrict__ Wout, const float* __restrict__ bout,
                           float* __restrict__ out) {
    __shared__ float red[4][64];
    __shared__ float sh[64];
    __shared__ float logits[OUT_DIM];
    int g = blockIdx.x;
    int t = threadIdx.x, f = t & 63, w = t >> 6;
    int lo = 0, hi = N_NODES;
    while (lo < hi) { int m = (lo + hi) >> 1; if (batch[m] < g) lo = m + 1; else hi = m; }
    int start = lo;
    hi = N_NODES;
    while (lo < hi) { int m = (lo + hi) >> 1; if (batch[m] < g + 1) lo = m + 1; else hi = m; }
    int end = lo;
    float a = 0.f;
    for (int i = start + w; i < end; i += 4)
        a += xm[(size_t)i * 64 + f];
    red[w][f] = a;
    __syncthreads();
    if (w == 0) {
        float cnt = (float)((end - start) > 0 ? (end - start) : 1);
        sh[f] = (red[0][f] + red[1][f] + red[2][f] + red[3][f]) / cnt;
    }
    __syncthreads();
    if (t < OUT_DIM) {
        float l = bout[t];
        for (int k = 0; k < 64; ++k) l += sh[k] * Wout[k * OUT_DIM + t];
        logits[t] = l;
    }
    __syncthreads();
    if (t < OUT_DIM) {
        float m = logits[0];
        for (int k = 1; k < OUT_DIM; ++k) m = fmaxf(m, logits[k]);
        float ssum = 0.f;
        for (int k = 0; k < OUT_DIM; ++k) ssum += expf(logits[k] - m);
        out[(size_t)g * OUT_DIM + t] = expf(logits[t] - m) / ssum;
    }
}

extern "C" void kernel_launch(void* const* d_in, const int* in_sizes, int n_in,
                              void* d_out, int out_size, void* d_ws, size_t ws_size,
                              hipStream_t stream) {
    const float* X     = (const float*)d_in[0];
    const int*   Lind  = (const int*)d_in[1];
    const int*   ind0  = Lind;
    const int*   ind1  = Lind + N_EDGES;
    const float* vals  = (const float*)d_in[2];
    const int*   batch = (const int*)d_in[3];
    const float* W1    = (const float*)d_in[4];
    const float* b1    = (const float*)d_in[5];
    const float* W2    = (const float*)d_in[6];
    const float* b2    = (const float*)d_in[7];
    const float* W3    = (const float*)d_in[8];
    const float* b3    = (const float*)d_in[9];
    const float* Wout  = (const float*)d_in[10];
    const float* bout  = (const float*)d_in[11];
    float* out = (float*)d_out;

    // workspace layout (4B words)
    int* cnt0    = (int*)d_ws;                        // 50000
    int* cnt1    = cnt0 + 50000;                      // 50000
    int* gcur    = cnt1 + 50000;                      // 400 (2*NRANGE used)
    uint2* c0seg = (uint2*)(gcur + 400);              // NRANGE*SEGCAP uint2
    unsigned int* c1seg = (unsigned int*)(c0seg + (size_t)NRANGE * SEGCAP);
    unsigned int* c0pack = c1seg + (size_t)NRANGE * SEGCAP;   // 2,400,000
    int*  c1src  = (int*)(c0pack + 50000 * CAP);      // 2,400,000
    uint2* G0bf  = (uint2*)(c1src + 50000 * CAP);     // 800,000 uint2 (8B aligned)
    uint2* G1bf  = G0bf + 800000;
    uint2* G2bf  = G1bf + 800000;
    uint2* Rbf   = G2bf + 800000;
    uint2* hbf   = Rbf + 800000;
    uint2* h2bf  = hbf + 800000;
    float* xm    = (float*)(h2bf + 800000);           // 3,200,000 fp32 (16B aligned)
    unsigned short* Xbf = (unsigned short*)(xm + 3200000);  // 6,400,000 ushort (16B aligned)
    unsigned short* Wsw = Xbf + 6400000;              // 24,576 ushort (16B aligned)
    // bf16 buffer reuse after producers die:
    uint2* x1bf  = G0bf;   // G0 dead after spmm1
    uint2* x2bf  = G1bf;   // G1 dead after spmm0

    const int B = 256;
    const int gatherGrid = 12500 * 64 / B;                // 3125 blocks (4 nodes/wave)

    // two-phase CSR build + bf16 prep
    k_zero_int<<<2, B, 0, stream>>>(gcur, 2 * NRANGE);
    k_binA<<<NCHUNKS, B, 0, stream>>>(ind0, ind1, vals, gcur, c0seg, c1seg);
    k_binB<<<2 * NRANGE, B, 0, stream>>>(gcur, c0seg, c1seg, c0pack, c1src, cnt0, cnt1);
    k_prep<<<48 + (N_NODES * IN_DIM / 4 + B - 1) / B, B, 0, stream>>>(X, W1, Xbf, Wsw);

    // layer-1 GEMMs via MFMA bf16 (no LDS, no barriers)
    k_gemm1mfma<<<GEMM_BLOCKS * 3, B, 0, stream>>>(Xbf, Wsw, G0bf, G1bf, G2bf);

    // Chebyshev via linearity (64-dim spmms, bf16 gathers):
    // R = G1 + 2*(L@G2);  h1' = dis*(L@R + G0 - G2)
    k_spmm64v<0><<<gatherGrid, B, 0, stream>>>(cnt0, c0pack, G2bf, G1bf, nullptr, cnt1, Rbf);
    k_spmm64v<1><<<gatherGrid, B, 0, stream>>>(cnt0, c0pack, Rbf, G0bf, G2bf, cnt1, hbf);

    // layer 1 conv + layer-2 GEMM fused: reads hbf, writes x1bf + h2bf
    k_conv_gemm<<<gatherGrid, B, 0, stream>>>(cnt1, c1src, hbf, b1, W2, x1bf, h2bf);

    // layer 2 conv + layer-3 GEMM fused: reads h2bf, writes x2bf + hbf
    k_conv_gemm<<<gatherGrid, B, 0, stream>>>(cnt1, c1src, h2bf, b2, W3, x2bf, hbf);

    // layer 3 conv (final): reads hbf, writes xm = (x1+x2+x3)/3
    k_conv_final<<<gatherGrid, B, 0, stream>>>(cnt1, c1src, hbf, b3, x1bf, x2bf, (float4*)xm);

    // pool + head
    k_pool_out<<<N_GRAPHS, B, 0, stream>>>(xm, batch, Wout, bout, out);
}

// Round 25
// 209.450 us; speedup vs baseline: 1.5659x; 1.0380x over previous
//
#include <hip/hip_runtime.h>
#include <hip/hip_bf16.h>
#include <hip/hip_fp16.h>

#define N_NODES 50000
#define N_EDGES 800000
#define IN_DIM 128
#define F_SIZE 64
#define N_GRAPHS 512
#define OUT_DIM 10
#define EDGE_CHUNK 2048
#define NCHUNKS ((N_EDGES + EDGE_CHUNK - 1) / EDGE_CHUNK)   // 391
#define GEMM_BLOCKS 782        // ceil(50000/64)
#define CAP 48                 // per-node CSR bucket capacity (max degree ~45 @ Poisson(16))
#define NRANGE 196             // node ranges of 256 (50000 >> 8 -> 0..195)
#define SEGCAP 4608            // entries per range segment (mean 4096, +8 sigma)
#define XCONV_BLOCKS ((N_NODES * IN_DIM / 4 + 255) / 256)   // 6250

typedef __attribute__((ext_vector_type(8))) short short8;
typedef __attribute__((ext_vector_type(4))) float f32x4;

// ---------------- bf16 pack/unpack helpers (round-to-nearest-even) ----------------
__device__ __forceinline__ unsigned int pack_bf2(float a, float b) {
    unsigned int ua = __float_as_uint(a);
    unsigned int ub = __float_as_uint(b);
    ua += 0x7fffu + ((ua >> 16) & 1u);
    ub += 0x7fffu + ((ub >> 16) & 1u);
    return (ua >> 16) | (ub & 0xffff0000u);
}
__device__ __forceinline__ uint2 pack_f4(float4 o) {
    return make_uint2(pack_bf2(o.x, o.y), pack_bf2(o.z, o.w));
}
__device__ __forceinline__ float4 unpack_f4(uint2 u) {
    float4 f;
    f.x = __uint_as_float(u.x << 16);
    f.y = __uint_as_float(u.x & 0xffff0000u);
    f.z = __uint_as_float(u.y << 16);
    f.w = __uint_as_float(u.y & 0xffff0000u);
    return f;
}
__device__ __forceinline__ unsigned short bf1(float x) {
    unsigned int u = __float_as_uint(x);
    u += 0x7fffu + ((u >> 16) & 1u);
    return (unsigned short)(u >> 16);
}

// ---------------- utility ----------------
__global__ void k_zero_int(int* __restrict__ p, int n) {
    int i = blockIdx.x * blockDim.x + threadIdx.x;
    if (i < n) p[i] = 0;
}

// ---------------- fused: Phase A edge binning (blocks < NCHUNKS) + bf16 prep (rest) ----------------
// Co-schedule is safe here (unlike R19): binA's seg writes are one-shot contiguous
// bursts, not long-lived partial bucket lines; both paths use <=3KB LDS.
__global__ __launch_bounds__(256) void k_binA_prep(const int* __restrict__ ind0,
                                                   const int* __restrict__ ind1,
                                                   const float* __restrict__ vals,
                                                   int* __restrict__ gcur,
                                                   uint2* __restrict__ c0seg,
                                                   unsigned int* __restrict__ c1seg,
                                                   const float* __restrict__ X,
                                                   const float* __restrict__ W1,
                                                   unsigned short* __restrict__ Xbf,
                                                   unsigned short* __restrict__ Wsw) {
    __shared__ int h0[NRANGE], h1[NRANGE], b0[NRANGE], b1[NRANGE];
    int t = threadIdx.x;
    if (blockIdx.x >= NCHUNKS) {
        int pblk = blockIdx.x - NCHUNKS;
        if (pblk < 48) {
            if (t < 64) {
                int frag = pblk;                // ((sg*4 + kt)*4 + ct)
                int ct = frag & 3;
                int kt = (frag >> 2) & 3;
                int sg = frag >> 4;
                #pragma unroll
                for (int j = 0; j < 8; ++j) {
                    int k = sg * 128 + kt * 32 + (t >> 4) * 8 + j;
                    int col = ct * 16 + (t & 15);
                    Wsw[frag * 512 + t * 8 + j] = bf1(W1[k * 64 + col]);
                }
            }
            return;
        }
        long idx = (long)(pblk - 48) * 256 + t;   // float4 id
        if (idx < (long)N_NODES * IN_DIM / 4) {
            float4 v = ((const float4*)X)[idx];
            ((uint2*)Xbf)[idx] = pack_f4(v);
        }
        return;
    }
    // ---- binA path ----
    if (t < NRANGE) { h0[t] = 0; h1[t] = 0; }
    __syncthreads();
    int base = blockIdx.x * EDGE_CHUNK;
    int r[8], c[8]; unsigned int hv[8];
    #pragma unroll
    for (int i = 0; i < 8; ++i) {
        int e = base + i * 256 + t;
        if (e < N_EDGES) {
            r[i] = ind0[e]; c[i] = ind1[e];
            hv[i] = (unsigned int)__half_as_ushort(__float2half(vals[e]));
            atomicAdd(&h0[r[i] >> 8], 1);
            atomicAdd(&h1[c[i] >> 8], 1);
        } else r[i] = -1;
    }
    __syncthreads();
    if (t < NRANGE) {
        b0[t] = atomicAdd(&gcur[t], h0[t]);
        b1[t] = atomicAdd(&gcur[NRANGE + t], h1[t]);
        h0[t] = 0; h1[t] = 0;
    }
    __syncthreads();
    #pragma unroll
    for (int i = 0; i < 8; ++i) {
        if (r[i] >= 0) {
            int bin0 = r[i] >> 8;
            int off0 = b0[bin0] + atomicAdd(&h0[bin0], 1);
            c0seg[(size_t)bin0 * SEGCAP + off0] =
                make_uint2(((unsigned int)(r[i] & 255) << 16) | hv[i], (unsigned int)c[i]);
            int bin1 = c[i] >> 8;
            int off1 = b1[bin1] + atomicAdd(&h1[bin1], 1);
            c1seg[(size_t)bin1 * SEGCAP + off1] =
                ((unsigned int)(c[i] & 255) << 16) | (unsigned int)r[i];
        }
    }
}

// ---------------- fused: Phase B counting build (blocks < 2*NRANGE) + MFMA gemm1 (rest) ----------------
__global__ __launch_bounds__(256) void k_binB_gemm(const int* __restrict__ gcur,
                                                   const uint2* __restrict__ c0seg,
                                                   const unsigned int* __restrict__ c1seg,
                                                   unsigned int* __restrict__ c0pack,
                                                   int* __restrict__ c1src,
                                                   int* __restrict__ cnt0,
                                                   int* __restrict__ cnt1,
                                                   const unsigned short* __restrict__ Xbf,
                                                   const unsigned short* __restrict__ Wsw,
                                                   uint2* __restrict__ G0bf,
                                                   uint2* __restrict__ G1bf,
                                                   uint2* __restrict__ G2bf) {
    __shared__ int cur[256];
    int t = threadIdx.x;
    if (blockIdx.x < 2 * NRANGE) {
        // ---- binB path ----
        int range = blockIdx.x >> 1;
        int side = blockIdx.x & 1;
        cur[t] = 0;
        __syncthreads();
        int nodeBase = range << 8;
        if (side == 0) {
            int n = gcur[range];
            for (int i = t; i < n; i += 256) {
                uint2 en = c0seg[(size_t)range * SEGCAP + i];
                int rlow = en.x >> 16;
                int node = nodeBase + rlow;
                int k = atomicAdd(&cur[rlow], 1);
                c0pack[(size_t)node * CAP + k] = (en.y << 16) | (en.x & 0xffffu);
            }
            __syncthreads();
            int node = nodeBase + t;
            if (node < N_NODES) cnt0[node] = cur[t];
        } else {
            int n = gcur[NRANGE + range];
            for (int i = t; i < n; i += 256) {
                unsigned int en = c1seg[(size_t)range * SEGCAP + i];
                int clow = (en >> 16) & 0xff;
                int node = nodeBase + clow;
                int k = atomicAdd(&cur[clow], 1);
                c1src[(size_t)node * CAP + k] = (int)(en & 0xffffu);
            }
            __syncthreads();
            int node = nodeBase + t;
            if (node < N_NODES) cnt1[node] = cur[t];
        }
        return;
    }
    // ---- MFMA gemm1 path: block = 64x64 tile x one W1 segment, no LDS/barriers ----
    int blk = blockIdx.x - 2 * NRANGE;
    int tile = blk / 3, sg = blk - tile * 3;
    int w = t >> 6, l = t & 63;
    int r0 = tile * 64 + w * 16;
    int arow = r0 + (l & 15); if (arow > N_NODES - 1) arow = N_NODES - 1;
    const unsigned short* ap = Xbf + (size_t)arow * IN_DIM + (l >> 4) * 8;
    short8 a[4];
    #pragma unroll
    for (int kt = 0; kt < 4; ++kt)
        a[kt] = *(const short8*)(ap + kt * 32);
    unsigned short* Gout_us = (unsigned short*)((sg == 0) ? G0bf : (sg == 1) ? G1bf : G2bf);
    #pragma unroll
    for (int ct = 0; ct < 4; ++ct) {
        f32x4 acc = {0.f, 0.f, 0.f, 0.f};
        #pragma unroll
        for (int kt = 0; kt < 4; ++kt) {
            short8 b = *(const short8*)(Wsw + ((size_t)((sg * 4 + kt) * 4 + ct)) * 512 + l * 8);
            acc = __builtin_amdgcn_mfma_f32_16x16x32_bf16(a[kt], b, acc, 0, 0, 0);
        }
        int col = ct * 16 + (l & 15);
        #pragma unroll
        for (int i = 0; i < 4; ++i) {
            int grow = r0 + (l >> 4) * 4 + i;
            if (grow < N_NODES)
                Gout_us[(size_t)grow * 64 + col] = bf1(acc[i]);
        }
    }
}

// ---------------- bf16-gather SpMM: wave = 4 nodes, 16 lanes/row ----------------
// MODE 0: Rbf = A(G1bf) + 2*acc(src=G2bf)
// MODE 1: hbf = dis*(acc(src=Rbf) + A(G0bf) - B(G2bf))
template<int MODE>
__global__ __launch_bounds__(256) void k_spmm64v(const int* __restrict__ cnt0,
                          const unsigned int* __restrict__ pack,
                          const uint2* __restrict__ srcbf, const uint2* __restrict__ Abf,
                          const uint2* __restrict__ Bbf, const int* __restrict__ cnt1,
                          uint2* __restrict__ dstbf) {
    int t = blockIdx.x * blockDim.x + threadIdx.x;
    int wid = t >> 6, lane = t & 63;
    int grp = lane >> 4, sub = lane & 15;
    int node = wid * 4 + grp;
    if (node >= N_NODES) return;
    int s = node * CAP;
    int e = s + cnt0[node];
    float4 acc = {0.f, 0.f, 0.f, 0.f};
    int j = s;
    for (; j + 3 < e; j += 4) {
        unsigned int p0 = pack[j], p1 = pack[j + 1], p2 = pack[j + 2], p3 = pack[j + 3];
        float4 r0 = unpack_f4(srcbf[(size_t)(p0 >> 16) * 16 + sub]);
        float4 r1 = unpack_f4(srcbf[(size_t)(p1 >> 16) * 16 + sub]);
        float4 r2 = unpack_f4(srcbf[(size_t)(p2 >> 16) * 16 + sub]);
        float4 r3 = unpack_f4(srcbf[(size_t)(p3 >> 16) * 16 + sub]);
        float v0 = __half2float(__ushort_as_half((unsigned short)(p0 & 0xffffu)));
        float v1 = __half2float(__ushort_as_half((unsigned short)(p1 & 0xffffu)));
        float v2 = __half2float(__ushort_as_half((unsigned short)(p2 & 0xffffu)));
        float v3 = __half2float(__ushort_as_half((unsigned short)(p3 & 0xffffu)));
        acc.x += v0 * r0.x + v1 * r1.x + v2 * r2.x + v3 * r3.x;
        acc.y += v0 * r0.y + v1 * r1.y + v2 * r2.y + v3 * r3.y;
        acc.z += v0 * r0.z + v1 * r1.z + v2 * r2.z + v3 * r3.z;
        acc.w += v0 * r0.w + v1 * r1.w + v2 * r2.w + v3 * r3.w;
    }
    for (; j < e; ++j) {
        unsigned int p = pack[j];
        float4 r = unpack_f4(srcbf[(size_t)(p >> 16) * 16 + sub]);
        float v = __half2float(__ushort_as_half((unsigned short)(p & 0xffffu)));
        acc.x += v * r.x; acc.y += v * r.y; acc.z += v * r.z; acc.w += v * r.w;
    }
    size_t idx = (size_t)node * 16 + sub;
    float4 a = unpack_f4(Abf[idx]);
    float4 o;
    if (MODE == 0) {
        o.x = a.x + 2.f * acc.x; o.y = a.y + 2.f * acc.y;
        o.z = a.z + 2.f * acc.z; o.w = a.w + 2.f * acc.w;
    } else {
        float4 bb = unpack_f4(Bbf[idx]);
        float d = rsqrtf(1.0f + (float)cnt1[node]);
        o.x = d * (acc.x + a.x - bb.x); o.y = d * (acc.y + a.y - bb.y);
        o.z = d * (acc.z + a.z - bb.z); o.w = d * (acc.w + a.w - bb.w);
    }
    dstbf[idx] = pack_f4(o);
}

// ---------------- fused conv + 64x64 GEMM: block = 16 nodes ----------------
__global__ __launch_bounds__(256) void k_conv_gemm(const int* __restrict__ cnt1,
                                                   const int* __restrict__ csrc,
                                                   const uint2* __restrict__ hin,
                                                   const float* __restrict__ b,
                                                   const float* __restrict__ W,
                                                   uint2* __restrict__ xout,
                                                   uint2* __restrict__ hout) {
    __shared__ float xl[16][64];
    __shared__ float4 Wl4[64 * 16];
    int t = threadIdx.x;
    int gt = blockIdx.x * 256 + t;
    int wid = gt >> 6, lane = t & 63;
    int grp = lane >> 4, sub = lane & 15;
    int node = wid * 4 + grp;
    int ln = ((t >> 6) << 2) + grp;
    int deg = cnt1[node];
    int s = node * CAP;
    int e = s + deg;
    float4 acc = {0.f, 0.f, 0.f, 0.f};
    int j = s;
    for (; j + 3 < e; j += 4) {
        int s0 = csrc[j], s1 = csrc[j + 1], s2 = csrc[j + 2], s3 = csrc[j + 3];
        float4 r0 = unpack_f4(hin[(size_t)s0 * 16 + sub]);
        float4 r1 = unpack_f4(hin[(size_t)s1 * 16 + sub]);
        float4 r2 = unpack_f4(hin[(size_t)s2 * 16 + sub]);
        float4 r3 = unpack_f4(hin[(size_t)s3 * 16 + sub]);
        acc.x += (r0.x + r1.x) + (r2.x + r3.x);
        acc.y += (r0.y + r1.y) + (r2.y + r3.y);
        acc.z += (r0.z + r1.z) + (r2.z + r3.z);
        acc.w += (r0.w + r1.w) + (r2.w + r3.w);
    }
    for (; j < e; ++j) {
        float4 r = unpack_f4(hin[(size_t)csrc[j] * 16 + sub]);
        acc.x += r.x; acc.y += r.y; acc.z += r.z; acc.w += r.w;
    }
    size_t idx = (size_t)node * 16 + sub;
    float4 sl = unpack_f4(hin[idx]);
    float d = rsqrtf(1.0f + (float)deg);
    float4 bv = ((const float4*)b)[sub];
    float4 o;
    o.x = fmaxf(d * (acc.x + sl.x) + bv.x, 0.f);
    o.y = fmaxf(d * (acc.y + sl.y) + bv.y, 0.f);
    o.z = fmaxf(d * (acc.z + sl.z) + bv.z, 0.f);
    o.w = fmaxf(d * (acc.w + sl.w) + bv.w, 0.f);
    xout[idx] = pack_f4(o);
    xl[ln][sub * 4 + 0] = o.x;
    xl[ln][sub * 4 + 1] = o.y;
    xl[ln][sub * 4 + 2] = o.z;
    xl[ln][sub * 4 + 3] = o.w;
    {
        const float4* Wg = (const float4*)W;
        #pragma unroll
        for (int i = 0; i < 4; ++i) Wl4[i * 256 + t] = Wg[i * 256 + t];
    }
    __syncthreads();
    int n = t >> 4, c4 = t & 15;
    float4 h4 = {0.f, 0.f, 0.f, 0.f};
    #pragma unroll 8
    for (int k = 0; k < 64; ++k) {
        float xv = xl[n][k];
        float4 w4 = Wl4[k * 16 + c4];
        h4.x += xv * w4.x; h4.y += xv * w4.y; h4.z += xv * w4.z; h4.w += xv * w4.w;
    }
    int gnode = blockIdx.x * 16 + n;
    float dn = rsqrtf(1.0f + (float)cnt1[gnode]);
    h4.x *= dn; h4.y *= dn; h4.z *= dn; h4.w *= dn;
    hout[(size_t)gnode * 16 + c4] = pack_f4(h4);
}

// ---------------- final conv: xm = bf16((x1 + x2 + relu(...))/3)  (feeds pool only) ----------------
__global__ void k_conv_final(const int* __restrict__ cnt1, const int* __restrict__ csrc,
                             const uint2* __restrict__ hin,
                             const float* __restrict__ b,
                             const uint2* __restrict__ x1bf, const uint2* __restrict__ x2bf,
                             uint2* __restrict__ xmbf) {
    int t = blockIdx.x * blockDim.x + threadIdx.x;
    int wid = t >> 6, lane = t & 63;
    int grp = lane >> 4, sub = lane & 15;
    int node = wid * 4 + grp;
    if (node >= N_NODES) return;
    int deg = cnt1[node];
    int s = node * CAP;
    int e = s + deg;
    float4 acc = {0.f, 0.f, 0.f, 0.f};
    int j = s;
    for (; j + 3 < e; j += 4) {
        int s0 = csrc[j], s1 = csrc[j + 1], s2 = csrc[j + 2], s3 = csrc[j + 3];
        float4 r0 = unpack_f4(hin[(size_t)s0 * 16 + sub]);
        float4 r1 = unpack_f4(hin[(size_t)s1 * 16 + sub]);
        float4 r2 = unpack_f4(hin[(size_t)s2 * 16 + sub]);
        float4 r3 = unpack_f4(hin[(size_t)s3 * 16 + sub]);
        acc.x += (r0.x + r1.x) + (r2.x + r3.x);
        acc.y += (r0.y + r1.y) + (r2.y + r3.y);
        acc.z += (r0.z + r1.z) + (r2.z + r3.z);
        acc.w += (r0.w + r1.w) + (r2.w + r3.w);
    }
    for (; j < e; ++j) {
        float4 r = unpack_f4(hin[(size_t)csrc[j] * 16 + sub]);
        acc.x += r.x; acc.y += r.y; acc.z += r.z; acc.w += r.w;
    }
    size_t idx = (size_t)node * 16 + sub;
    float4 sl = unpack_f4(hin[idx]);
    float d = rsqrtf(1.0f + (float)deg);
    float4 bv = ((const float4*)b)[sub];
    float4 o;
    o.x = fmaxf(d * (acc.x + sl.x) + bv.x, 0.f);
    o.y = fmaxf(d * (acc.y + sl.y) + bv.y, 0.f);
    o.z = fmaxf(d * (acc.z + sl.z) + bv.z, 0.f);
    o.w = fmaxf(d * (acc.w + sl.w) + bv.w, 0.f);
    float4 a1 = unpack_f4(x1bf[idx]), a2 = unpack_f4(x2bf[idx]);
    const float third = 1.f / 3.f;
    o.x = (a1.x + a2.x + o.x) * third;
    o.y = (a1.y + a2.y + o.y) * third;
    o.z = (a1.z + a2.z + o.z) * third;
    o.w = (a1.w + a2.w + o.w) * third;
    xmbf[idx] = pack_f4(o);
}

// ---------------- pool (batch sorted -> contiguous ranges) + head, 4 waves ----------------
__global__ __launch_bounds__(256) void k_pool_out(const unsigned short* __restrict__ xm_us,
                           const int* __restrict__ batch,
                           const float* __restrict__ Wout, const float* __restrict__ bout,
                           float* __restrict__ out) {
    __shared__ float red[4][64];
    __shared__ float sh[64];
    __shared__ float logits[OUT_DIM];
    int g = blockIdx.x;
    int t = threadIdx.x, f = t & 63, w = t >> 6;
    int lo = 0, hi = N_NODES;
    while (lo < hi) { int m = (lo + hi) >> 1; if (batch[m] < g) lo = m + 1; else hi = m; }
    int start = lo;
    hi = N_NODES;
    while (lo < hi) { int m = (lo + hi) >> 1; if (batch[m] < g + 1) lo = m + 1; else hi = m; }
    int end = lo;
    float a = 0.f;
    for (int i = start + w; i < end; i += 4)
        a += __uint_as_float((unsigned int)xm_us[(size_t)i * 64 + f] << 16);
    red[w][f] = a;
    __syncthreads();
    if (w == 0) {
        float cnt = (float)((end - start) > 0 ? (end - start) : 1);
        sh[f] = (red[0][f] + red[1][f] + red[2][f] + red[3][f]) / cnt;
    }
    __syncthreads();
    if (t < OUT_DIM) {
        float l = bout[t];
        for (int k = 0; k < 64; ++k) l += sh[k] * Wout[k * OUT_DIM + t];
        logits[t] = l;
    }
    __syncthreads();
    if (t < OUT_DIM) {
        float m = logits[0];
        for (int k = 1; k < OUT_DIM; ++k) m = fmaxf(m, logits[k]);
        float ssum = 0.f;
        for (int k = 0; k < OUT_DIM; ++k) ssum += expf(logits[k] - m);
        out[(size_t)g * OUT_DIM + t] = expf(logits[t] - m) / ssum;
    }
}

extern "C" void kernel_launch(void* const* d_in, const int* in_sizes, int n_in,
                              void* d_out, int out_size, void* d_ws, size_t ws_size,
                              hipStream_t stream) {
    const float* X     = (const float*)d_in[0];
    const int*   Lind  = (const int*)d_in[1];
    const int*   ind0  = Lind;
    const int*   ind1  = Lind + N_EDGES;
    const float* vals  = (const float*)d_in[2];
    const int*   batch = (const int*)d_in[3];
    const float* W1    = (const float*)d_in[4];
    const float* b1    = (const float*)d_in[5];
    const float* W2    = (const float*)d_in[6];
    const float* b2    = (const float*)d_in[7];
    const float* W3    = (const float*)d_in[8];
    const float* b3    = (const float*)d_in[9];
    const float* Wout  = (const float*)d_in[10];
    const float* bout  = (const float*)d_in[11];
    float* out = (float*)d_out;

    // workspace layout (4B words)
    int* cnt0    = (int*)d_ws;                        // 50000
    int* cnt1    = cnt0 + 50000;                      // 50000
    int* gcur    = cnt1 + 50000;                      // 400 (2*NRANGE used)
    uint2* c0seg = (uint2*)(gcur + 400);              // NRANGE*SEGCAP uint2
    unsigned int* c1seg = (unsigned int*)(c0seg + (size_t)NRANGE * SEGCAP);
    unsigned int* c0pack = c1seg + (size_t)NRANGE * SEGCAP;   // 2,400,000
    int*  c1src  = (int*)(c0pack + 50000 * CAP);      // 2,400,000
    uint2* G0bf  = (uint2*)(c1src + 50000 * CAP);     // 800,000 uint2 (8B aligned)
    uint2* G1bf  = G0bf + 800000;
    uint2* G2bf  = G1bf + 800000;
    uint2* Rbf   = G2bf + 800000;
    uint2* hbf   = Rbf + 800000;
    uint2* h2bf  = hbf + 800000;
    uint2* xmbf  = h2bf + 800000;                     // 800,000 uint2 (bf16 xm)
    unsigned short* Xbf = (unsigned short*)(xmbf + 800000);   // 6,400,000 ushort
    unsigned short* Wsw = Xbf + 6400000;              // 24,576 ushort
    // bf16 buffer reuse after producers die:
    uint2* x1bf  = G0bf;   // G0 dead after spmm1
    uint2* x2bf  = G1bf;   // G1 dead after spmm0

    const int B = 256;
    const int gatherGrid = 12500 * 64 / B;                // 3125 blocks (4 nodes/wave)

    // fused CSR build + bf16 prep + MFMA gemm1
    k_zero_int<<<2, B, 0, stream>>>(gcur, 2 * NRANGE);
    k_binA_prep<<<NCHUNKS + 48 + XCONV_BLOCKS, B, 0, stream>>>(ind0, ind1, vals, gcur,
                                                               c0seg, c1seg, X, W1, Xbf, Wsw);
    k_binB_gemm<<<2 * NRANGE + GEMM_BLOCKS * 3, B, 0, stream>>>(gcur, c0seg, c1seg,
                                                                c0pack, c1src, cnt0, cnt1,
                                                                Xbf, Wsw, G0bf, G1bf, G2bf);

    // Chebyshev via linearity (64-dim spmms, bf16 gathers):
    // R = G1 + 2*(L@G2);  h1' = dis*(L@R + G0 - G2)
    k_spmm64v<0><<<gatherGrid, B, 0, stream>>>(cnt0, c0pack, G2bf, G1bf, nullptr, cnt1, Rbf);
    k_spmm64v<1><<<gatherGrid, B, 0, stream>>>(cnt0, c0pack, Rbf, G0bf, G2bf, cnt1, hbf);

    // layer 1 conv + layer-2 GEMM fused: reads hbf, writes x1bf + h2bf
    k_conv_gemm<<<gatherGrid, B, 0, stream>>>(cnt1, c1src, hbf, b1, W2, x1bf, h2bf);

    // layer 2 conv + layer-3 GEMM fused: reads h2bf, writes x2bf + hbf
    k_conv_gemm<<<gatherGrid, B, 0, stream>>>(cnt1, c1src, h2bf, b2, W3, x2bf, hbf);

    // layer 3 conv (final): reads hbf, writes xm (bf16) = (x1+x2+x3)/3
    k_conv_final<<<gatherGrid, B, 0, stream>>>(cnt1, c1src, hbf, b3, x1bf, x2bf, xmbf);

    // pool + head
    k_pool_out<<<N_GRAPHS, B, 0, stream>>>((const unsigned short*)xmbf, batch, Wout, bout, out);
}